// Round 9
// baseline (448.012 us; speedup 1.0000x reference)
//
#include <hip/hip_runtime.h>
#include <stdint.h>

typedef __attribute__((ext_vector_type(8))) short short8;
typedef __attribute__((ext_vector_type(4))) float floatx4;

__device__ __forceinline__ unsigned short f2bf(float x) {
    unsigned int u = __builtin_bit_cast(unsigned int, x);
    unsigned int r = (u + 0x7FFFu + ((u >> 16) & 1u)) >> 16;   // RNE
    return (unsigned short)r;
}

// tanh = (e^2x-1)/(e^2x+1), clamp |x|<=10; rcp + 1 Newton. ~1e-7 rel err.
__device__ __forceinline__ float fast_tanh(float x) {
    float xc = fminf(fmaxf(x, -10.0f), 10.0f);
    float e  = __expf(2.0f * xc);
    float d  = e + 1.0f;
    float r  = __builtin_amdgcn_rcpf(d);
    r = r * (2.0f - d * r);
    return (e - 1.0f) * r;
}

// ---- W f32 -> bf16 ----
__global__ void wconv(const float4* __restrict__ W4, ushort4* __restrict__ Wb4) {
    int i = blockIdx.x * 256 + threadIdx.x;
    float4 v = W4[i];
    ushort4 o;
    o.x = f2bf(v.x); o.y = f2bf(v.y); o.z = f2bf(v.z); o.w = f2bf(v.w);
    Wb4[i] = o;
}

// ---- level 0: h0 = bf16(tanh(emb[ids])), [131072][512], 8 elems/thread ----
__global__ void embed_tanh(const int* __restrict__ ids, const float* __restrict__ emb,
                           ushort* __restrict__ h0) {
    int idx = blockIdx.x * 256 + threadIdx.x;   // 8,388,608 threads
    int e = idx * 8;
    int row = e >> 9;
    int col = e & 511;
    int id = ids[row];
    const float* src = emb + (size_t)id * 512 + col;
    const float4 v0 = *reinterpret_cast<const float4*>(src);
    const float4 v1 = *reinterpret_cast<const float4*>(src + 4);
    short8 o;
    o[0] = (short)f2bf(fast_tanh(v0.x)); o[1] = (short)f2bf(fast_tanh(v0.y));
    o[2] = (short)f2bf(fast_tanh(v0.z)); o[3] = (short)f2bf(fast_tanh(v0.w));
    o[4] = (short)f2bf(fast_tanh(v1.x)); o[5] = (short)f2bf(fast_tanh(v1.y));
    o[6] = (short)f2bf(fast_tanh(v1.z)); o[7] = (short)f2bf(fast_tanh(v1.w));
    *reinterpret_cast<short8*>(h0 + e) = o;
}

// ======== shared GEMM-core macros ========
#define STAGE_(sA, sB, Ap, Bp, buf, k0)                                         \
    do {                                                                        \
        __builtin_amdgcn_global_load_lds(                                       \
            (const __attribute__((address_space(1))) void*)((Ap) + (k0)),       \
            (__attribute__((address_space(3))) void*)&sA[buf][tid * 8], 16, 0, 0); \
        __builtin_amdgcn_global_load_lds(                                       \
            (const __attribute__((address_space(1))) void*)((Ap) + 64 * 1024 + (k0)), \
            (__attribute__((address_space(3))) void*)&sA[buf][2048 + tid * 8], 16, 0, 0); \
        __builtin_amdgcn_global_load_lds(                                       \
            (const __attribute__((address_space(1))) void*)((Bp) + (k0)),       \
            (__attribute__((address_space(3))) void*)&sB[buf][tid * 8], 16, 0, 0); \
        __builtin_amdgcn_global_load_lds(                                       \
            (const __attribute__((address_space(1))) void*)((Bp) + 64 * 1024 + (k0)), \
            (__attribute__((address_space(3))) void*)&sB[buf][2048 + tid * 8], 16, 0, 0); \
    } while (0)

#define COMPUTE_(sA, sB, cur)                                                   \
    do {                                                                        \
        short8 a_[4], b_[4];                                                    \
        _Pragma("unroll")                                                       \
        for (int mi = 0; mi < 4; ++mi)                                          \
            a_[mi] = *reinterpret_cast<const short8*>(&sA[cur][(rA + mi * 16) * 32 + kksw]); \
        _Pragma("unroll")                                                       \
        for (int ni = 0; ni < 4; ++ni)                                          \
            b_[ni] = *reinterpret_cast<const short8*>(&sB[cur][(rB + ni * 16) * 32 + kksw]); \
        __builtin_amdgcn_s_setprio(1);                                          \
        _Pragma("unroll")                                                       \
        for (int mi = 0; mi < 4; ++mi)                                          \
            _Pragma("unroll")                                                   \
            for (int ni = 0; ni < 4; ++ni)                                      \
                acc[mi][ni] = __builtin_amdgcn_mfma_f32_16x16x32_bf16(          \
                    a_[mi], b_[ni], acc[mi][ni], 0, 0, 0);                      \
        __builtin_amdgcn_s_setprio(0);                                          \
    } while (0)

// ---- validated round-3 loop (1-deep, barrier-first): used by level_gemm ----
#define KLOOP_(sA, sB, Ap, Bp)                                                  \
    do {                                                                        \
        STAGE_(sA, sB, Ap, Bp, 0, 0);                                           \
        STAGE_(sA, sB, Ap, Bp, 1, 32);                                          \
        for (int t = 0; t < 30; t += 3) {                                       \
            asm volatile("s_barrier" ::: "memory");                             \
            STAGE_(sA, sB, Ap, Bp, 2, (t + 2) * 32);                            \
            asm volatile("s_waitcnt vmcnt(4)" ::: "memory");                    \
            COMPUTE_(sA, sB, 0);                                                \
            asm volatile("s_barrier" ::: "memory");                             \
            STAGE_(sA, sB, Ap, Bp, 0, (t + 3) * 32);                            \
            asm volatile("s_waitcnt vmcnt(4)" ::: "memory");                    \
            COMPUTE_(sA, sB, 1);                                                \
            asm volatile("s_barrier" ::: "memory");                             \
            STAGE_(sA, sB, Ap, Bp, 1, (t + 4) * 32);                            \
            asm volatile("s_waitcnt vmcnt(4)" ::: "memory");                    \
            COMPUTE_(sA, sB, 2);                                                \
        }                                                                       \
        asm volatile("s_barrier" ::: "memory");                                 \
        asm volatile("s_waitcnt vmcnt(0)" ::: "memory");                        \
        COMPUTE_(sA, sB, 0);                                                    \
        asm volatile("s_barrier" ::: "memory");                                 \
        asm volatile("s_waitcnt vmcnt(0)" ::: "memory");                        \
        COMPUTE_(sA, sB, 1);                                                    \
    } while (0)

// ---- levels 1..5: out[M][512] = tanh(A[M][1024] @ W^T + b), M >= 4096 ----
__global__ __launch_bounds__(256)
void level_gemm(const ushort* __restrict__ A, const ushort* __restrict__ Bt,
                const float* __restrict__ bias,
                ushort* __restrict__ outb, int M)
{
    const int nb  = gridDim.x;
    int bid = blockIdx.x;
    const int per = nb >> 3;                       // nb always multiple of 8 here
    const int lin = (bid & 7) * per + (bid >> 3);  // bijective XCD chunking
    const int mt = lin >> 2, nt = lin & 3;
    const int m0 = mt * 128, n0 = nt * 128;

    __shared__ alignas(16) ushort sA[3][4096];
    __shared__ alignas(16) ushort sB[3][4096];

    const int tid  = threadIdx.x;
    const int lane = tid & 63;
    const int w    = tid >> 6;
    const int wr   = w >> 1, wc = w & 1;

    const int sr    = tid >> 2;
    const int swcol = (((tid & 3) ^ ((tid >> 3) & 3)) << 3);
    const ushort* Ap = A  + (size_t)(m0 + sr) * 1024 + swcol;
    const ushort* Bp = Bt + (size_t)(n0 + sr) * 1024 + swcol;

    const int rA   = wr * 64 + (lane & 15);
    const int rB   = wc * 64 + (lane & 15);
    const int kksw = (((lane >> 4) ^ ((lane >> 1) & 3)) << 3);

    floatx4 acc[4][4] = {};
    KLOOP_(sA, sB, Ap, Bp);

    const int mrow = (lane >> 4) * 4;
    const int ncol = lane & 15;
    #pragma unroll
    for (int mi = 0; mi < 4; ++mi) {
        #pragma unroll
        for (int ni = 0; ni < 4; ++ni) {
            const int n = n0 + wc * 64 + ni * 16 + ncol;
            const float bb = bias[n];
            #pragma unroll
            for (int j = 0; j < 4; ++j) {
                const int m = m0 + wr * 64 + mi * 16 + mrow + j;
                float v = fast_tanh(acc[mi][ni][j] + bb);
                outb[(size_t)m * 512 + n] = f2bf(v);
            }
        }
    }
}

// ---- software grid barrier, RMW-polled.
// Round-7 lesson: acquire-poll emits buffer_inv per poll (L2 nuke, 202us).
// Round-8 lesson: relaxed LOAD poll is served by the spinner's stale local
// XCD L2 -> update invisible until eviction (~25us/level, 160us).
// Fix: poll with atomic fetch_add(0) — an RMW executes at the coherence
// point (same mechanism that makes cross-XCD atomicAdd correct), so it is
// promptly coherent and has no cache-invalidate side effect.
__device__ __forceinline__ void grid_bar(unsigned* bar, unsigned target, bool did_work) {
    __syncthreads();
    if (threadIdx.x == 0) {
        if (did_work) {
            __threadfence();   // release: flush my stores to coherence point
            __hip_atomic_fetch_add(bar, 1u, __ATOMIC_RELEASE, __HIP_MEMORY_SCOPE_AGENT);
        } else {
            __hip_atomic_fetch_add(bar, 1u, __ATOMIC_RELAXED, __HIP_MEMORY_SCOPE_AGENT);
        }
        while (__hip_atomic_fetch_add(bar, 0u, __ATOMIC_RELAXED,
                                      __HIP_MEMORY_SCOPE_AGENT) < target)
            __builtin_amdgcn_s_sleep(8);
        __threadfence();   // acquire once: drop stale lines before next level
    }
    __syncthreads();
}

// ---- levels 6..11 fused: 64 blocks, grid barrier between levels.
// Latency-bound (1 block/CU): depth-4 prefetch, 6 LDS buffers (96 KiB).
__global__ __launch_bounds__(256)
void tail6(const ushort* __restrict__ Bt, const float* __restrict__ bias,
           ushort* __restrict__ hA, ushort* __restrict__ hB,
           float* __restrict__ out, unsigned* bar)
{
    __shared__ alignas(16) ushort sA[6][4096];
    __shared__ alignas(16) ushort sB[6][4096];

    const int tid  = threadIdx.x;
    const int lane = tid & 63;
    const int w    = tid >> 6;
    const int wr   = w >> 1, wc = w & 1;
    const int bid  = blockIdx.x;

    const int sr    = tid >> 2;
    const int swcol = (((tid & 3) ^ ((tid >> 3) & 3)) << 3);
    const int rA    = wr * 64 + (lane & 15);
    const int rB    = wc * 64 + (lane & 15);
    const int kksw  = (((lane >> 4) ^ ((lane >> 1) & 3)) << 3);
    const int mrow  = (lane >> 4) * 4;
    const int ncol  = lane & 15;

    int M = 2048;
    for (int lev = 0; lev < 6; ++lev, M >>= 1) {
        const ushort* src = (lev & 1) ? hA : hB;
        ushort*       dst = (lev & 1) ? hB : hA;
        const int T = ((M + 127) >> 7) * 4;
        const bool work = (bid < T);
        if (work) {
            const int mt = bid >> 2, nt = bid & 3;
            const int m0 = mt * 128, n0 = nt * 128;
            const ushort* Ap = src + (size_t)(m0 + sr) * 1024 + swcol;
            const ushort* Bp = Bt  + (size_t)(n0 + sr) * 1024 + swcol;

            floatx4 acc[4][4] = {};

            STAGE_(sA, sB, Ap, Bp, 0, 0);
            STAGE_(sA, sB, Ap, Bp, 1, 32);
            STAGE_(sA, sB, Ap, Bp, 2, 64);
            STAGE_(sA, sB, Ap, Bp, 3, 96);
            for (int t = 0; t < 28; ++t) {
                const int sb = (t + 4) % 6;
                STAGE_(sA, sB, Ap, Bp, sb, (t + 4) * 32);
                asm volatile("s_waitcnt vmcnt(16)" ::: "memory");  // retire tile t
                asm volatile("s_barrier" ::: "memory");
                COMPUTE_(sA, sB, t % 6);
            }
            for (int t = 28; t < 32; ++t) {
                switch (31 - t) {
                    case 3: asm volatile("s_waitcnt vmcnt(12)" ::: "memory"); break;
                    case 2: asm volatile("s_waitcnt vmcnt(8)"  ::: "memory"); break;
                    case 1: asm volatile("s_waitcnt vmcnt(4)"  ::: "memory"); break;
                    default: asm volatile("s_waitcnt vmcnt(0)" ::: "memory"); break;
                }
                asm volatile("s_barrier" ::: "memory");
                COMPUTE_(sA, sB, t % 6);
            }

            #pragma unroll
            for (int mi = 0; mi < 4; ++mi) {
                #pragma unroll
                for (int ni = 0; ni < 4; ++ni) {
                    const int n = n0 + wc * 64 + ni * 16 + ncol;
                    const float bb = bias[n];
                    #pragma unroll
                    for (int j = 0; j < 4; ++j) {
                        const int m = m0 + wr * 64 + mi * 16 + mrow + j;
                        if (m < M) {
                            float v = fast_tanh(acc[mi][ni][j] + bb);
                            if (lev == 5) out[(size_t)m * 512 + n] = v;  // roots, f32
                            else          dst[(size_t)m * 512 + n] = f2bf(v);
                        }
                    }
                }
            }
        }
        if (lev < 5) grid_bar(bar, (unsigned)((lev + 1) * gridDim.x), work);
    }
}

extern "C" void kernel_launch(void* const* d_in, const int* in_sizes, int n_in,
                              void* d_out, int out_size, void* d_ws, size_t ws_size,
                              hipStream_t stream) {
    const int*   ids  = (const int*)d_in[0];
    const float* emb  = (const float*)d_in[1];
    const float* W    = (const float*)d_in[2];
    const float* bias = (const float*)d_in[3];
    float* out = (float*)d_out;

    unsigned short* Wb = (unsigned short*)d_ws;        // 1 MiB
    unsigned short* hA = Wb + 524288;                  // 128 MiB region
    unsigned short* hB = hA + 67108864;                // 64 MiB region
    // bar at hB+32MiB: clobbered by level-1 writes, so zero it AFTER level 5
    // (stream-ordered) and before tail6. tail6 writes at most hB+1MiB. Safe.
    unsigned* bar = (unsigned*)(hB + 16777216);

    wconv<<<512, 256, 0, stream>>>((const float4*)W, (ushort4*)Wb);
    embed_tanh<<<32768, 256, 0, stream>>>(ids, emb, hA);

    int M = 65536;
    for (int l = 1; l <= 5; ++l) {                     // outputs: hB,hA,hB,hA,hB
        const unsigned short* in = (l & 1) ? hA : hB;
        unsigned short*       ob = (l & 1) ? hB : hA;
        int gm = M / 128;
        level_gemm<<<gm * 4, 256, 0, stream>>>(in, Wb, bias, ob, M);
        M >>= 1;
    }
    (void)hipMemsetAsync((void*)bar, 0, 4, stream);    // zero AFTER lev5 writes hB
    tail6<<<64, 256, 0, stream>>>(Wb, bias, hA, hB, out, bar);  // levels 6..11
}

// Round 10
// 432.727 us; speedup vs baseline: 1.0353x; 1.0353x over previous
//
#include <hip/hip_runtime.h>
#include <stdint.h>

typedef __attribute__((ext_vector_type(8))) short short8;
typedef __attribute__((ext_vector_type(4))) float floatx4;

__device__ __forceinline__ unsigned short f2bf(float x) {
    unsigned int u = __builtin_bit_cast(unsigned int, x);
    unsigned int r = (u + 0x7FFFu + ((u >> 16) & 1u)) >> 16;   // RNE
    return (unsigned short)r;
}

// tanh = (e^2x-1)/(e^2x+1), clamp |x|<=10; rcp + 1 Newton. ~1e-7 rel err.
__device__ __forceinline__ float fast_tanh(float x) {
    float xc = fminf(fmaxf(x, -10.0f), 10.0f);
    float e  = __expf(2.0f * xc);
    float d  = e + 1.0f;
    float r  = __builtin_amdgcn_rcpf(d);
    r = r * (2.0f - d * r);
    return (e - 1.0f) * r;
}

// ---- W f32 -> bf16 ----
__global__ void wconv(const float4* __restrict__ W4, ushort4* __restrict__ Wb4) {
    int i = blockIdx.x * 256 + threadIdx.x;
    float4 v = W4[i];
    ushort4 o;
    o.x = f2bf(v.x); o.y = f2bf(v.y); o.z = f2bf(v.z); o.w = f2bf(v.w);
    Wb4[i] = o;
}

// ---- level 0: h0 = bf16(tanh(emb[ids])), [131072][512], 8 elems/thread ----
__global__ void embed_tanh(const int* __restrict__ ids, const float* __restrict__ emb,
                           ushort* __restrict__ h0) {
    int idx = blockIdx.x * 256 + threadIdx.x;   // 8,388,608 threads
    int e = idx * 8;
    int row = e >> 9;
    int col = e & 511;
    int id = ids[row];
    const float* src = emb + (size_t)id * 512 + col;
    const float4 v0 = *reinterpret_cast<const float4*>(src);
    const float4 v1 = *reinterpret_cast<const float4*>(src + 4);
    short8 o;
    o[0] = (short)f2bf(fast_tanh(v0.x)); o[1] = (short)f2bf(fast_tanh(v0.y));
    o[2] = (short)f2bf(fast_tanh(v0.z)); o[3] = (short)f2bf(fast_tanh(v0.w));
    o[4] = (short)f2bf(fast_tanh(v1.x)); o[5] = (short)f2bf(fast_tanh(v1.y));
    o[6] = (short)f2bf(fast_tanh(v1.z)); o[7] = (short)f2bf(fast_tanh(v1.w));
    *reinterpret_cast<short8*>(h0 + e) = o;
}

// ======== shared GEMM-core macros ========
#define STAGE_(sA, sB, Ap, Bp, buf, k0)                                         \
    do {                                                                        \
        __builtin_amdgcn_global_load_lds(                                       \
            (const __attribute__((address_space(1))) void*)((Ap) + (k0)),       \
            (__attribute__((address_space(3))) void*)&sA[buf][tid * 8], 16, 0, 0); \
        __builtin_amdgcn_global_load_lds(                                       \
            (const __attribute__((address_space(1))) void*)((Ap) + 64 * 1024 + (k0)), \
            (__attribute__((address_space(3))) void*)&sA[buf][2048 + tid * 8], 16, 0, 0); \
        __builtin_amdgcn_global_load_lds(                                       \
            (const __attribute__((address_space(1))) void*)((Bp) + (k0)),       \
            (__attribute__((address_space(3))) void*)&sB[buf][tid * 8], 16, 0, 0); \
        __builtin_amdgcn_global_load_lds(                                       \
            (const __attribute__((address_space(1))) void*)((Bp) + 64 * 1024 + (k0)), \
            (__attribute__((address_space(3))) void*)&sB[buf][2048 + tid * 8], 16, 0, 0); \
    } while (0)

#define COMPUTE_(sA, sB, cur)                                                   \
    do {                                                                        \
        short8 a_[4], b_[4];                                                    \
        _Pragma("unroll")                                                       \
        for (int mi = 0; mi < 4; ++mi)                                          \
            a_[mi] = *reinterpret_cast<const short8*>(&sA[cur][(rA + mi * 16) * 32 + kksw]); \
        _Pragma("unroll")                                                       \
        for (int ni = 0; ni < 4; ++ni)                                          \
            b_[ni] = *reinterpret_cast<const short8*>(&sB[cur][(rB + ni * 16) * 32 + kksw]); \
        __builtin_amdgcn_s_setprio(1);                                          \
        _Pragma("unroll")                                                       \
        for (int mi = 0; mi < 4; ++mi)                                          \
            _Pragma("unroll")                                                   \
            for (int ni = 0; ni < 4; ++ni)                                      \
                acc[mi][ni] = __builtin_amdgcn_mfma_f32_16x16x32_bf16(          \
                    a_[mi], b_[ni], acc[mi][ni], 0, 0, 0);                      \
        __builtin_amdgcn_s_setprio(0);                                          \
    } while (0)

// ---- validated round-3 loop (1-deep, barrier-first): used by level_gemm ----
#define KLOOP_(sA, sB, Ap, Bp)                                                  \
    do {                                                                        \
        STAGE_(sA, sB, Ap, Bp, 0, 0);                                           \
        STAGE_(sA, sB, Ap, Bp, 1, 32);                                          \
        for (int t = 0; t < 30; t += 3) {                                       \
            asm volatile("s_barrier" ::: "memory");                             \
            STAGE_(sA, sB, Ap, Bp, 2, (t + 2) * 32);                            \
            asm volatile("s_waitcnt vmcnt(4)" ::: "memory");                    \
            COMPUTE_(sA, sB, 0);                                                \
            asm volatile("s_barrier" ::: "memory");                             \
            STAGE_(sA, sB, Ap, Bp, 0, (t + 3) * 32);                            \
            asm volatile("s_waitcnt vmcnt(4)" ::: "memory");                    \
            COMPUTE_(sA, sB, 1);                                                \
            asm volatile("s_barrier" ::: "memory");                             \
            STAGE_(sA, sB, Ap, Bp, 1, (t + 4) * 32);                            \
            asm volatile("s_waitcnt vmcnt(4)" ::: "memory");                    \
            COMPUTE_(sA, sB, 2);                                                \
        }                                                                       \
        asm volatile("s_barrier" ::: "memory");                                 \
        asm volatile("s_waitcnt vmcnt(0)" ::: "memory");                        \
        COMPUTE_(sA, sB, 0);                                                    \
        asm volatile("s_barrier" ::: "memory");                                 \
        asm volatile("s_waitcnt vmcnt(0)" ::: "memory");                        \
        COMPUTE_(sA, sB, 1);                                                    \
    } while (0)

// ---- levels 1..5: out[M][512] = tanh(A[M][1024] @ W^T + b), M >= 4096 ----
__global__ __launch_bounds__(256)
void level_gemm(const ushort* __restrict__ A, const ushort* __restrict__ Bt,
                const float* __restrict__ bias,
                ushort* __restrict__ outb, int M)
{
    const int nb  = gridDim.x;
    int bid = blockIdx.x;
    const int per = nb >> 3;                       // nb always multiple of 8 here
    const int lin = (bid & 7) * per + (bid >> 3);  // bijective XCD chunking
    const int mt = lin >> 2, nt = lin & 3;
    const int m0 = mt * 128, n0 = nt * 128;

    __shared__ alignas(16) ushort sA[3][4096];
    __shared__ alignas(16) ushort sB[3][4096];

    const int tid  = threadIdx.x;
    const int lane = tid & 63;
    const int w    = tid >> 6;
    const int wr   = w >> 1, wc = w & 1;

    const int sr    = tid >> 2;
    const int swcol = (((tid & 3) ^ ((tid >> 3) & 3)) << 3);
    const ushort* Ap = A  + (size_t)(m0 + sr) * 1024 + swcol;
    const ushort* Bp = Bt + (size_t)(n0 + sr) * 1024 + swcol;

    const int rA   = wr * 64 + (lane & 15);
    const int rB   = wc * 64 + (lane & 15);
    const int kksw = (((lane >> 4) ^ ((lane >> 1) & 3)) << 3);

    floatx4 acc[4][4] = {};
    KLOOP_(sA, sB, Ap, Bp);

    const int mrow = (lane >> 4) * 4;
    const int ncol = lane & 15;
    #pragma unroll
    for (int mi = 0; mi < 4; ++mi) {
        #pragma unroll
        for (int ni = 0; ni < 4; ++ni) {
            const int n = n0 + wc * 64 + ni * 16 + ncol;
            const float bb = bias[n];
            #pragma unroll
            for (int j = 0; j < 4; ++j) {
                const int m = m0 + wr * 64 + mi * 16 + mrow + j;
                float v = fast_tanh(acc[mi][ni][j] + bb);
                outb[(size_t)m * 512 + n] = f2bf(v);
            }
        }
    }
}

// ---- levels 6..11: small-M per-level GEMM, latency-optimized.
// Depth-4 prefetch, 6 LDS buffers (96 KiB, 1 block/CU — grid <= 64 anyway).
// Validated in rounds 7-9 (inside tail6); here launched per level so the
// stream provides inter-level sync (~2us) instead of a ~22us grid barrier.
__global__ __launch_bounds__(256)
void tail_gemm(const ushort* __restrict__ A, const ushort* __restrict__ Bt,
               const float* __restrict__ bias,
               ushort* __restrict__ outb, float* __restrict__ outf,
               int M, int last)
{
    __shared__ alignas(16) ushort sA[6][4096];
    __shared__ alignas(16) ushort sB[6][4096];

    const int tid  = threadIdx.x;
    const int lane = tid & 63;
    const int w    = tid >> 6;
    const int wr   = w >> 1, wc = w & 1;
    const int mt   = blockIdx.x >> 2, nt = blockIdx.x & 3;
    const int m0   = mt * 128, n0 = nt * 128;

    const int sr    = tid >> 2;
    const int swcol = (((tid & 3) ^ ((tid >> 3) & 3)) << 3);
    const ushort* Ap = A  + (size_t)(m0 + sr) * 1024 + swcol;
    const ushort* Bp = Bt + (size_t)(n0 + sr) * 1024 + swcol;

    const int rA   = wr * 64 + (lane & 15);
    const int rB   = wc * 64 + (lane & 15);
    const int kksw = (((lane >> 4) ^ ((lane >> 1) & 3)) << 3);

    floatx4 acc[4][4] = {};

    STAGE_(sA, sB, Ap, Bp, 0, 0);
    STAGE_(sA, sB, Ap, Bp, 1, 32);
    STAGE_(sA, sB, Ap, Bp, 2, 64);
    STAGE_(sA, sB, Ap, Bp, 3, 96);
    for (int t = 0; t < 28; ++t) {
        STAGE_(sA, sB, Ap, Bp, (t + 4) % 6, (t + 4) * 32);
        asm volatile("s_waitcnt vmcnt(16)" ::: "memory");  // retire tile t
        asm volatile("s_barrier" ::: "memory");
        COMPUTE_(sA, sB, t % 6);
    }
    for (int t = 28; t < 32; ++t) {
        switch (31 - t) {
            case 3: asm volatile("s_waitcnt vmcnt(12)" ::: "memory"); break;
            case 2: asm volatile("s_waitcnt vmcnt(8)"  ::: "memory"); break;
            case 1: asm volatile("s_waitcnt vmcnt(4)"  ::: "memory"); break;
            default: asm volatile("s_waitcnt vmcnt(0)" ::: "memory"); break;
        }
        asm volatile("s_barrier" ::: "memory");
        COMPUTE_(sA, sB, t % 6);
    }

    const int mrow = (lane >> 4) * 4;
    const int ncol = lane & 15;
    #pragma unroll
    for (int mi = 0; mi < 4; ++mi) {
        #pragma unroll
        for (int ni = 0; ni < 4; ++ni) {
            const int n = n0 + wc * 64 + ni * 16 + ncol;
            const float bb = bias[n];
            #pragma unroll
            for (int j = 0; j < 4; ++j) {
                const int m = m0 + wr * 64 + mi * 16 + mrow + j;
                if (m < M) {
                    float v = fast_tanh(acc[mi][ni][j] + bb);
                    if (last) outf[(size_t)m * 512 + n] = v;
                    else      outb[(size_t)m * 512 + n] = f2bf(v);
                }
            }
        }
    }
}

extern "C" void kernel_launch(void* const* d_in, const int* in_sizes, int n_in,
                              void* d_out, int out_size, void* d_ws, size_t ws_size,
                              hipStream_t stream) {
    const int*   ids  = (const int*)d_in[0];
    const float* emb  = (const float*)d_in[1];
    const float* W    = (const float*)d_in[2];
    const float* bias = (const float*)d_in[3];
    float* out = (float*)d_out;

    unsigned short* Wb = (unsigned short*)d_ws;        // 1 MiB
    unsigned short* hA = Wb + 524288;                  // 128 MiB region
    unsigned short* hB = hA + 67108864;                // 64 MiB region

    wconv<<<512, 256, 0, stream>>>((const float4*)W, (ushort4*)Wb);
    embed_tanh<<<32768, 256, 0, stream>>>(ids, emb, hA);

    int M = 65536;
    for (int l = 1; l <= 5; ++l) {                     // outputs: hB,hA,hB,hA,hB
        const unsigned short* in = (l & 1) ? hA : hB;
        unsigned short*       ob = (l & 1) ? hB : hA;
        int gm = M / 128;
        level_gemm<<<gm * 4, 256, 0, stream>>>(in, Wb, bias, ob, M);
        M >>= 1;
    }
    // levels 6..11: M = 2048,1024,512,256,128,64; ping-pong continues (hB->hA->...)
    for (int l = 6; l <= 11; ++l) {
        const unsigned short* in = (l & 1) ? hA : hB;
        unsigned short*       ob = (l & 1) ? hB : hA;
        int nbk = ((M + 127) / 128) * 4;
        tail_gemm<<<nbk, 256, 0, stream>>>(in, Wb, bias, ob, out, M, l == 11 ? 1 : 0);
        M >>= 1;
    }
}

// Round 11
// 418.513 us; speedup vs baseline: 1.0705x; 1.0340x over previous
//
#include <hip/hip_runtime.h>
#include <stdint.h>

typedef __attribute__((ext_vector_type(8))) short short8;
typedef __attribute__((ext_vector_type(4))) float floatx4;

__device__ __forceinline__ unsigned short f2bf(float x) {
    unsigned int u = __builtin_bit_cast(unsigned int, x);
    unsigned int r = (u + 0x7FFFu + ((u >> 16) & 1u)) >> 16;   // RNE
    return (unsigned short)r;
}

// tanh = (e^2x-1)/(e^2x+1), clamp |x|<=10; rcp + 1 Newton. ~1e-7 rel err.
__device__ __forceinline__ float fast_tanh(float x) {
    float xc = fminf(fmaxf(x, -10.0f), 10.0f);
    float e  = __expf(2.0f * xc);
    float d  = e + 1.0f;
    float r  = __builtin_amdgcn_rcpf(d);
    r = r * (2.0f - d * r);
    return (e - 1.0f) * r;
}

// ---- W f32 -> bf16 ----
__global__ void wconv(const float4* __restrict__ W4, ushort4* __restrict__ Wb4) {
    int i = blockIdx.x * 256 + threadIdx.x;
    float4 v = W4[i];
    ushort4 o;
    o.x = f2bf(v.x); o.y = f2bf(v.y); o.z = f2bf(v.z); o.w = f2bf(v.w);
    Wb4[i] = o;
}

// ---- level 0: h0 = bf16(tanh(emb[ids])), [131072][512], 8 elems/thread ----
__global__ void embed_tanh(const int* __restrict__ ids, const float* __restrict__ emb,
                           ushort* __restrict__ h0) {
    int idx = blockIdx.x * 256 + threadIdx.x;   // 8,388,608 threads
    int e = idx * 8;
    int row = e >> 9;
    int col = e & 511;
    int id = ids[row];
    const float* src = emb + (size_t)id * 512 + col;
    const float4 v0 = *reinterpret_cast<const float4*>(src);
    const float4 v1 = *reinterpret_cast<const float4*>(src + 4);
    short8 o;
    o[0] = (short)f2bf(fast_tanh(v0.x)); o[1] = (short)f2bf(fast_tanh(v0.y));
    o[2] = (short)f2bf(fast_tanh(v0.z)); o[3] = (short)f2bf(fast_tanh(v0.w));
    o[4] = (short)f2bf(fast_tanh(v1.x)); o[5] = (short)f2bf(fast_tanh(v1.y));
    o[6] = (short)f2bf(fast_tanh(v1.z)); o[7] = (short)f2bf(fast_tanh(v1.w));
    *reinterpret_cast<short8*>(h0 + e) = o;
}

// ======== shared GEMM-core macros (validated rounds 3-10) ========
#define STAGE_(sA, sB, Ap, Bp, buf, k0)                                         \
    do {                                                                        \
        __builtin_amdgcn_global_load_lds(                                       \
            (const __attribute__((address_space(1))) void*)((Ap) + (k0)),       \
            (__attribute__((address_space(3))) void*)&sA[buf][tid * 8], 16, 0, 0); \
        __builtin_amdgcn_global_load_lds(                                       \
            (const __attribute__((address_space(1))) void*)((Ap) + 64 * 1024 + (k0)), \
            (__attribute__((address_space(3))) void*)&sA[buf][2048 + tid * 8], 16, 0, 0); \
        __builtin_amdgcn_global_load_lds(                                       \
            (const __attribute__((address_space(1))) void*)((Bp) + (k0)),       \
            (__attribute__((address_space(3))) void*)&sB[buf][tid * 8], 16, 0, 0); \
        __builtin_amdgcn_global_load_lds(                                       \
            (const __attribute__((address_space(1))) void*)((Bp) + 64 * 1024 + (k0)), \
            (__attribute__((address_space(3))) void*)&sB[buf][2048 + tid * 8], 16, 0, 0); \
    } while (0)

#define COMPUTE_(sA, sB, cur)                                                   \
    do {                                                                        \
        short8 a_[4], b_[4];                                                    \
        _Pragma("unroll")                                                       \
        for (int mi = 0; mi < 4; ++mi)                                          \
            a_[mi] = *reinterpret_cast<const short8*>(&sA[cur][(rA + mi * 16) * 32 + kksw]); \
        _Pragma("unroll")                                                       \
        for (int ni = 0; ni < 4; ++ni)                                          \
            b_[ni] = *reinterpret_cast<const short8*>(&sB[cur][(rB + ni * 16) * 32 + kksw]); \
        __builtin_amdgcn_s_setprio(1);                                          \
        _Pragma("unroll")                                                       \
        for (int mi = 0; mi < 4; ++mi)                                          \
            _Pragma("unroll")                                                   \
            for (int ni = 0; ni < 4; ++ni)                                      \
                acc[mi][ni] = __builtin_amdgcn_mfma_f32_16x16x32_bf16(          \
                    a_[mi], b_[ni], acc[mi][ni], 0, 0, 0);                      \
        __builtin_amdgcn_s_setprio(0);                                          \
    } while (0)

#define KLOOP_(sA, sB, Ap, Bp)                                                  \
    do {                                                                        \
        STAGE_(sA, sB, Ap, Bp, 0, 0);                                           \
        STAGE_(sA, sB, Ap, Bp, 1, 32);                                          \
        for (int t = 0; t < 30; t += 3) {                                       \
            asm volatile("s_barrier" ::: "memory");                             \
            STAGE_(sA, sB, Ap, Bp, 2, (t + 2) * 32);                            \
            asm volatile("s_waitcnt vmcnt(4)" ::: "memory");                    \
            COMPUTE_(sA, sB, 0);                                                \
            asm volatile("s_barrier" ::: "memory");                             \
            STAGE_(sA, sB, Ap, Bp, 0, (t + 3) * 32);                            \
            asm volatile("s_waitcnt vmcnt(4)" ::: "memory");                    \
            COMPUTE_(sA, sB, 1);                                                \
            asm volatile("s_barrier" ::: "memory");                             \
            STAGE_(sA, sB, Ap, Bp, 1, (t + 4) * 32);                            \
            asm volatile("s_waitcnt vmcnt(4)" ::: "memory");                    \
            COMPUTE_(sA, sB, 2);                                                \
        }                                                                       \
        asm volatile("s_barrier" ::: "memory");                                 \
        asm volatile("s_waitcnt vmcnt(0)" ::: "memory");                        \
        COMPUTE_(sA, sB, 0);                                                    \
        asm volatile("s_barrier" ::: "memory");                                 \
        asm volatile("s_waitcnt vmcnt(0)" ::: "memory");                        \
        COMPUTE_(sA, sB, 1);                                                    \
    } while (0)

// ---- levels 1..5: out[M][512] = tanh(A[M][1024] @ W^T + b), M >= 4096 ----
__global__ __launch_bounds__(256)
void level_gemm(const ushort* __restrict__ A, const ushort* __restrict__ Bt,
                const float* __restrict__ bias,
                ushort* __restrict__ outb, int M)
{
    const int nb  = gridDim.x;
    int bid = blockIdx.x;
    const int per = nb >> 3;                       // nb always multiple of 8 here
    const int lin = (bid & 7) * per + (bid >> 3);  // bijective XCD chunking
    const int mt = lin >> 2, nt = lin & 3;
    const int m0 = mt * 128, n0 = nt * 128;

    __shared__ alignas(16) ushort sA[3][4096];
    __shared__ alignas(16) ushort sB[3][4096];

    const int tid  = threadIdx.x;
    const int lane = tid & 63;
    const int w    = tid >> 6;
    const int wr   = w >> 1, wc = w & 1;

    const int sr    = tid >> 2;
    const int swcol = (((tid & 3) ^ ((tid >> 3) & 3)) << 3);
    const ushort* Ap = A  + (size_t)(m0 + sr) * 1024 + swcol;
    const ushort* Bp = Bt + (size_t)(n0 + sr) * 1024 + swcol;

    const int rA   = wr * 64 + (lane & 15);
    const int rB   = wc * 64 + (lane & 15);
    const int kksw = (((lane >> 4) ^ ((lane >> 1) & 3)) << 3);

    floatx4 acc[4][4] = {};
    KLOOP_(sA, sB, Ap, Bp);

    const int mrow = (lane >> 4) * 4;
    const int ncol = lane & 15;
    #pragma unroll
    for (int mi = 0; mi < 4; ++mi) {
        #pragma unroll
        for (int ni = 0; ni < 4; ++ni) {
            const int n = n0 + wc * 64 + ni * 16 + ncol;
            const float bb = bias[n];
            #pragma unroll
            for (int j = 0; j < 4; ++j) {
                const int m = m0 + wr * 64 + mi * 16 + mrow + j;
                float v = fast_tanh(acc[mi][ni][j] + bb);
                outb[(size_t)m * 512 + n] = f2bf(v);
            }
        }
    }
}

// ---- levels 6..11 fused per-tree: ONE launch, NO grid sync (trees independent).
// 64 blocks (1/tree) x 256 threads (4 waves). Per level: out[Mout][512] =
// tanh(A[Mout][1024] @ W^T + b), Mout = 32,16,8,4,2,1.
//   - W streamed through 3 LDS buffers [512][32] (96 KiB) with the validated
//     stage-2-ahead + vmcnt(8) pipeline (8 global_load_lds per stage).
//   - A read once per K-step into regs, reused across all 8 N-frags/wave.
//     Level 6 reads A direct from global h5; levels 7+ from LDS h ping-pong
//     (48 KiB, slot-XOR swizzled: phys = r*512 + (((c>>3)^((r>>1)&7))<<3)+(c&7)).
//   - Always 2 M-frags (rows >= Mout are clamped reads + masked writes).
__global__ __launch_bounds__(256)
void tree6(const ushort* __restrict__ h5, const ushort* __restrict__ Wb,
           const float* __restrict__ bias, float* __restrict__ out)
{
    __shared__ alignas(16) ushort wb[3][16384];   // [buf][n*32 + k], 96 KiB
    __shared__ alignas(16) ushort hb[24576];      // R0: rows 0..31; R1 at 16384: rows 0..15

    const int tid  = threadIdx.x;
    const int lane = tid & 63;
    const int w    = tid >> 6;
    const int l15  = lane & 15;
    const int lh   = lane >> 4;          // 0..3 (k sub-slot)
    const int tree = blockIdx.x;

    const ushort* gA = h5 + (size_t)tree * 64 * 512;

    float bb[8];
    #pragma unroll
    for (int nf = 0; nf < 8; ++nf) bb[nf] = bias[w * 128 + nf * 16 + l15];

    // staging decomposition: thread tid, rep i -> chunk c = i*256+tid;
    // n = i*64 + (tid>>2), slot = tid&3; LDS dst byte = c*16 (linear, = n*64+slot*16);
    // global col pre-swizzled so LDS(n,slot) = W(n, slot^((n>>1)&3)).
    const int sn    = tid >> 2;
    const int sslot = tid & 3;

#define STAGE_W(buf, k0)                                                        \
    do {                                                                        \
        _Pragma("unroll")                                                       \
        for (int i = 0; i < 8; ++i) {                                           \
            const int n_  = i * 64 + sn;                                        \
            const int gc_ = (k0) + ((sslot ^ ((n_ >> 1) & 3)) << 3);            \
            __builtin_amdgcn_global_load_lds(                                   \
                (const __attribute__((address_space(1))) void*)(Wb + (size_t)n_ * 1024 + gc_), \
                (__attribute__((address_space(3))) void*)&wb[buf][(i * 256 + tid) * 8], \
                16, 0, 0);                                                      \
        }                                                                       \
    } while (0)

    floatx4 acc[2][8];

#define COMP_T(tt, buf)                                                         \
    do {                                                                        \
        const int kk_ = ((tt) & 15) * 32 + lh * 8;      /* col 0..511 */        \
        const int p_  = (tt) >> 4;                      /* child select */      \
        short8 a_[2];                                                           \
        _Pragma("unroll")                                                       \
        for (int mi = 0; mi < 2; ++mi) {                                        \
            int r_ = l15 + mi * 16;                                             \
            if (r_ >= Mout) r_ = Mout - 1;              /* clamp: garbage-safe */ \
            const int ar_ = 2 * r_ + p_;                                        \
            if (lev == 0) {                                                     \
                a_[mi] = *reinterpret_cast<const short8*>(gA + ar_ * 512 + kk_); \
            } else {                                                            \
                const int ph_ = ar_ * 512 + ((((kk_ >> 3) ^ ((ar_ >> 1) & 7))) << 3); \
                a_[mi] = *reinterpret_cast<const short8*>(&hsrc[ph_]);          \
            }                                                                   \
        }                                                                       \
        __builtin_amdgcn_s_setprio(1);                                          \
        _Pragma("unroll")                                                       \
        for (int nf = 0; nf < 8; ++nf) {                                        \
            const int n_  = w * 128 + nf * 16 + l15;                            \
            const int bk_ = n_ * 32 + ((lh ^ ((n_ >> 1) & 3)) << 3);            \
            const short8 b_ = *reinterpret_cast<const short8*>(&wb[buf][bk_]);  \
            acc[0][nf] = __builtin_amdgcn_mfma_f32_16x16x32_bf16(a_[0], b_, acc[0][nf], 0, 0, 0); \
            acc[1][nf] = __builtin_amdgcn_mfma_f32_16x16x32_bf16(a_[1], b_, acc[1][nf], 0, 0, 0); \
        }                                                                       \
        __builtin_amdgcn_s_setprio(0);                                          \
    } while (0)

    for (int lev = 0; lev < 6; ++lev) {
        const int Mout = 32 >> lev;
        const ushort* hsrc = (lev & 1) ? hb + 16384 : hb;   // lev1<-R0? no: see below
        // src: lev1 reads R0 (hb), lev2 reads R1, lev3 R0, lev4 R1, lev5 R0.
        // (lev&1)? R1 : R0 gives lev1->R0? lev1&1=1 -> R1. Wrong; recompute:
        // dst parity: lev even -> R0, lev odd -> R1. src(lev) = dst(lev-1):
        const ushort* hs = ((lev & 1) ? hb : hb + 16384);   // lev odd src R0? lev1: dst(0)=R0 ✓ -> hs must be R0 when lev odd
        hsrc = (lev & 1) ? hb : hb + 16384;                 // lev1->R0, lev2->R1, lev3->R0... ✓
        (void)hs;
        ushort* hdst = (lev & 1) ? hb + 16384 : hb;         // lev0->R0, lev1->R1, lev2->R0 ✓

        #pragma unroll
        for (int mi = 0; mi < 2; ++mi)
            #pragma unroll
            for (int nf = 0; nf < 8; ++nf) acc[mi][nf] = (floatx4){0.f, 0.f, 0.f, 0.f};

        STAGE_W(0, 0);
        STAGE_W(1, 32);
        for (int t3 = 0; t3 < 30; t3 += 3) {
            asm volatile("s_barrier" ::: "memory");
            STAGE_W(2, (t3 + 2) * 32);
            asm volatile("s_waitcnt vmcnt(8)" ::: "memory");
            COMP_T(t3 + 0, 0);
            asm volatile("s_barrier" ::: "memory");
            STAGE_W(0, (t3 + 3) * 32);
            asm volatile("s_waitcnt vmcnt(8)" ::: "memory");
            COMP_T(t3 + 1, 1);
            asm volatile("s_barrier" ::: "memory");
            STAGE_W(1, (t3 + 4) * 32);
            asm volatile("s_waitcnt vmcnt(8)" ::: "memory");
            COMP_T(t3 + 2, 2);
        }
        asm volatile("s_barrier" ::: "memory");
        asm volatile("s_waitcnt vmcnt(8)" ::: "memory");    // tile30 already retired
        COMP_T(30, 0);
        asm volatile("s_barrier" ::: "memory");
        asm volatile("s_waitcnt vmcnt(0)" ::: "memory");
        COMP_T(31, 1);

        // epilogue
        #pragma unroll
        for (int mi = 0; mi < 2; ++mi) {
            #pragma unroll
            for (int nf = 0; nf < 8; ++nf) {
                const int n = w * 128 + nf * 16 + l15;
                #pragma unroll
                for (int j = 0; j < 4; ++j) {
                    const int r = mi * 16 + lh * 4 + j;
                    if (r < Mout) {
                        float v = fast_tanh(acc[mi][nf][j] + bb[nf]);
                        if (lev == 5) out[(size_t)tree * 512 + n] = v;   // root (r==0)
                        else hdst[r * 512 + (((n >> 3) ^ ((r >> 1) & 7)) << 3) + (n & 7)] = f2bf(v);
                    }
                }
            }
        }
        __syncthreads();   // h visibility + wbuf WAR before next level
    }
#undef COMP_T
#undef STAGE_W
}

extern "C" void kernel_launch(void* const* d_in, const int* in_sizes, int n_in,
                              void* d_out, int out_size, void* d_ws, size_t ws_size,
                              hipStream_t stream) {
    const int*   ids  = (const int*)d_in[0];
    const float* emb  = (const float*)d_in[1];
    const float* W    = (const float*)d_in[2];
    const float* bias = (const float*)d_in[3];
    float* out = (float*)d_out;

    unsigned short* Wb = (unsigned short*)d_ws;        // 1 MiB
    unsigned short* hA = Wb + 524288;                  // 128 MiB region
    unsigned short* hB = hA + 67108864;                // 64 MiB region

    wconv<<<512, 256, 0, stream>>>((const float4*)W, (ushort4*)Wb);
    embed_tanh<<<32768, 256, 0, stream>>>(ids, emb, hA);

    int M = 65536;
    for (int l = 1; l <= 5; ++l) {                     // outputs: hB,hA,hB,hA,hB
        const unsigned short* in = (l & 1) ? hA : hB;
        unsigned short*       ob = (l & 1) ? hB : hA;
        int gm = M / 128;
        level_gemm<<<gm * 4, 256, 0, stream>>>(in, Wb, bias, ob, M);
        M >>= 1;
    }
    tree6<<<64, 256, 0, stream>>>(hB, Wb, bias, out);  // levels 6..11, one launch
}

// Round 12
// 333.920 us; speedup vs baseline: 1.3417x; 1.2533x over previous
//
#include <hip/hip_runtime.h>
#include <stdint.h>

typedef __attribute__((ext_vector_type(8))) short short8;
typedef __attribute__((ext_vector_type(4))) float floatx4;

__device__ __forceinline__ unsigned short f2bf(float x) {
    unsigned int u = __builtin_bit_cast(unsigned int, x);
    unsigned int r = (u + 0x7FFFu + ((u >> 16) & 1u)) >> 16;   // RNE
    return (unsigned short)r;
}

// tanh = (e^2x-1)/(e^2x+1), clamp |x|<=10; rcp + 1 Newton. ~1e-7 rel err.
__device__ __forceinline__ float fast_tanh(float x) {
    float xc = fminf(fmaxf(x, -10.0f), 10.0f);
    float e  = __expf(2.0f * xc);
    float d  = e + 1.0f;
    float r  = __builtin_amdgcn_rcpf(d);
    r = r * (2.0f - d * r);
    return (e - 1.0f) * r;
}

// ---- W f32 -> bf16 ----
__global__ void wconv(const float4* __restrict__ W4, ushort4* __restrict__ Wb4) {
    int i = blockIdx.x * 256 + threadIdx.x;
    float4 v = W4[i];
    ushort4 o;
    o.x = f2bf(v.x); o.y = f2bf(v.y); o.z = f2bf(v.z); o.w = f2bf(v.w);
    Wb4[i] = o;
}

// ---- level 0: h0 = bf16(tanh(emb[ids])), [131072][512], 8 elems/thread ----
__global__ void embed_tanh(const int* __restrict__ ids, const float* __restrict__ emb,
                           ushort* __restrict__ h0) {
    int idx = blockIdx.x * 256 + threadIdx.x;   // 8,388,608 threads
    int e = idx * 8;
    int row = e >> 9;
    int col = e & 511;
    int id = ids[row];
    const float* src = emb + (size_t)id * 512 + col;
    const float4 v0 = *reinterpret_cast<const float4*>(src);
    const float4 v1 = *reinterpret_cast<const float4*>(src + 4);
    short8 o;
    o[0] = (short)f2bf(fast_tanh(v0.x)); o[1] = (short)f2bf(fast_tanh(v0.y));
    o[2] = (short)f2bf(fast_tanh(v0.z)); o[3] = (short)f2bf(fast_tanh(v0.w));
    o[4] = (short)f2bf(fast_tanh(v1.x)); o[5] = (short)f2bf(fast_tanh(v1.y));
    o[6] = (short)f2bf(fast_tanh(v1.z)); o[7] = (short)f2bf(fast_tanh(v1.w));
    *reinterpret_cast<short8*>(h0 + e) = o;
}

// ======== shared GEMM-core macros (validated rounds 3-10) ========
#define STAGE_(sA, sB, Ap, Bp, buf, k0)                                         \
    do {                                                                        \
        __builtin_amdgcn_global_load_lds(                                       \
            (const __attribute__((address_space(1))) void*)((Ap) + (k0)),       \
            (__attribute__((address_space(3))) void*)&sA[buf][tid * 8], 16, 0, 0); \
        __builtin_amdgcn_global_load_lds(                                       \
            (const __attribute__((address_space(1))) void*)((Ap) + 64 * 1024 + (k0)), \
            (__attribute__((address_space(3))) void*)&sA[buf][2048 + tid * 8], 16, 0, 0); \
        __builtin_amdgcn_global_load_lds(                                       \
            (const __attribute__((address_space(1))) void*)((Bp) + (k0)),       \
            (__attribute__((address_space(3))) void*)&sB[buf][tid * 8], 16, 0, 0); \
        __builtin_amdgcn_global_load_lds(                                       \
            (const __attribute__((address_space(1))) void*)((Bp) + 64 * 1024 + (k0)), \
            (__attribute__((address_space(3))) void*)&sB[buf][2048 + tid * 8], 16, 0, 0); \
    } while (0)

#define COMPUTE_(sA, sB, cur)                                                   \
    do {                                                                        \
        short8 a_[4], b_[4];                                                    \
        _Pragma("unroll")                                                       \
        for (int mi = 0; mi < 4; ++mi)                                          \
            a_[mi] = *reinterpret_cast<const short8*>(&sA[cur][(rA + mi * 16) * 32 + kksw]); \
        _Pragma("unroll")                                                       \
        for (int ni = 0; ni < 4; ++ni)                                          \
            b_[ni] = *reinterpret_cast<const short8*>(&sB[cur][(rB + ni * 16) * 32 + kksw]); \
        __builtin_amdgcn_s_setprio(1);                                          \
        _Pragma("unroll")                                                       \
        for (int mi = 0; mi < 4; ++mi)                                          \
            _Pragma("unroll")                                                   \
            for (int ni = 0; ni < 4; ++ni)                                      \
                acc[mi][ni] = __builtin_amdgcn_mfma_f32_16x16x32_bf16(          \
                    a_[mi], b_[ni], acc[mi][ni], 0, 0, 0);                      \
        __builtin_amdgcn_s_setprio(0);                                          \
    } while (0)

#define KLOOP_(sA, sB, Ap, Bp)                                                  \
    do {                                                                        \
        STAGE_(sA, sB, Ap, Bp, 0, 0);                                           \
        STAGE_(sA, sB, Ap, Bp, 1, 32);                                          \
        for (int t = 0; t < 30; t += 3) {                                       \
            asm volatile("s_barrier" ::: "memory");                             \
            STAGE_(sA, sB, Ap, Bp, 2, (t + 2) * 32);                            \
            asm volatile("s_waitcnt vmcnt(4)" ::: "memory");                    \
            COMPUTE_(sA, sB, 0);                                                \
            asm volatile("s_barrier" ::: "memory");                             \
            STAGE_(sA, sB, Ap, Bp, 0, (t + 3) * 32);                            \
            asm volatile("s_waitcnt vmcnt(4)" ::: "memory");                    \
            COMPUTE_(sA, sB, 1);                                                \
            asm volatile("s_barrier" ::: "memory");                             \
            STAGE_(sA, sB, Ap, Bp, 1, (t + 4) * 32);                            \
            asm volatile("s_waitcnt vmcnt(4)" ::: "memory");                    \
            COMPUTE_(sA, sB, 2);                                                \
        }                                                                       \
        asm volatile("s_barrier" ::: "memory");                                 \
        asm volatile("s_waitcnt vmcnt(0)" ::: "memory");                        \
        COMPUTE_(sA, sB, 0);                                                    \
        asm volatile("s_barrier" ::: "memory");                                 \
        asm volatile("s_waitcnt vmcnt(0)" ::: "memory");                        \
        COMPUTE_(sA, sB, 1);                                                    \
    } while (0)

// ---- levels 1..4: out[M][512] = tanh(A[M][1024] @ W^T + b), M >= 8192 ----
__global__ __launch_bounds__(256)
void level_gemm(const ushort* __restrict__ A, const ushort* __restrict__ Bt,
                const float* __restrict__ bias,
                ushort* __restrict__ outb, int M)
{
    const int nb  = gridDim.x;
    int bid = blockIdx.x;
    const int per = nb >> 3;                       // nb always multiple of 8 here
    const int lin = (bid & 7) * per + (bid >> 3);  // bijective XCD chunking
    const int mt = lin >> 2, nt = lin & 3;
    const int m0 = mt * 128, n0 = nt * 128;

    __shared__ alignas(16) ushort sA[3][4096];
    __shared__ alignas(16) ushort sB[3][4096];

    const int tid  = threadIdx.x;
    const int lane = tid & 63;
    const int w    = tid >> 6;
    const int wr   = w >> 1, wc = w & 1;

    const int sr    = tid >> 2;
    const int swcol = (((tid & 3) ^ ((tid >> 3) & 3)) << 3);
    const ushort* Ap = A  + (size_t)(m0 + sr) * 1024 + swcol;
    const ushort* Bp = Bt + (size_t)(n0 + sr) * 1024 + swcol;

    const int rA   = wr * 64 + (lane & 15);
    const int rB   = wc * 64 + (lane & 15);
    const int kksw = (((lane >> 4) ^ ((lane >> 1) & 3)) << 3);

    floatx4 acc[4][4] = {};
    KLOOP_(sA, sB, Ap, Bp);

    const int mrow = (lane >> 4) * 4;
    const int ncol = lane & 15;
    #pragma unroll
    for (int mi = 0; mi < 4; ++mi) {
        #pragma unroll
        for (int ni = 0; ni < 4; ++ni) {
            const int n = n0 + wc * 64 + ni * 16 + ncol;
            const float bb = bias[n];
            #pragma unroll
            for (int j = 0; j < 4; ++j) {
                const int m = m0 + wr * 64 + mi * 16 + mrow + j;
                float v = fast_tanh(acc[mi][ni][j] + bb);
                outb[(size_t)m * 512 + n] = f2bf(v);
            }
        }
    }
}

// ---- levels 5..11: 64x64-tile GEMM, grid = (Mout/64) x 8 N-slices.
// Round-11 diagnosis: all previous tails were limited by per-CU W-streaming
// (~56 B/cy/CU L2 port). Small tiles spread each level's W over 8x more CUs:
// per-block traffic = 128KB A + 128KB B. BK=64, 16 K-steps, 3 LDS buffers
// (48KB), stage-2-ahead, counted vmcnt (4 loads/stage -> vmcnt(4) steady).
// XOR swizzle: 128B rows, slot ^= r&7 (inverse on global source col).
__global__ __launch_bounds__(256)
void small_gemm(const ushort* __restrict__ A, const ushort* __restrict__ Bt,
                const float* __restrict__ bias,
                ushort* __restrict__ outb, float* __restrict__ outf, int last)
{
    __shared__ alignas(16) ushort sA[3][4096];   // [buf][64 rows x 64 elems]
    __shared__ alignas(16) ushort sB[3][4096];

    const int tid  = threadIdx.x;
    const int lane = tid & 63;
    const int w    = tid >> 6;          // wave 0..3 -> N-sub w*16
    const int l15  = lane & 15;
    const int lh   = lane >> 4;         // 0..3
    const int mt   = blockIdx.x >> 3, nt = blockIdx.x & 7;
    const int m0   = mt * 64, n0 = nt * 64;

    // staging: thread stages chunks tid and 256+tid (rows r0, r0+32, same slot).
    const int r0 = tid >> 3;            // 0..31
    const int s0 = tid & 7;             // 16B slot in 128B row
    const int swz = ((s0 ^ (r0 & 7)) << 3);   // (r0+32)&7 == r0&7 -> same
    const ushort* Ap = A  + (size_t)(m0 + r0) * 1024 + swz;
    const ushort* Bp = Bt + (size_t)(n0 + r0) * 1024 + swz;

#define STG6(buf, k0)                                                           \
    do {                                                                        \
        __builtin_amdgcn_global_load_lds(                                       \
            (const __attribute__((address_space(1))) void*)(Ap + (k0)),         \
            (__attribute__((address_space(3))) void*)&sA[buf][tid * 8], 16, 0, 0); \
        __builtin_amdgcn_global_load_lds(                                       \
            (const __attribute__((address_space(1))) void*)(Ap + 32 * 1024 + (k0)), \
            (__attribute__((address_space(3))) void*)&sA[buf][2048 + tid * 8], 16, 0, 0); \
        __builtin_amdgcn_global_load_lds(                                       \
            (const __attribute__((address_space(1))) void*)(Bp + (k0)),         \
            (__attribute__((address_space(3))) void*)&sB[buf][tid * 8], 16, 0, 0); \
        __builtin_amdgcn_global_load_lds(                                       \
            (const __attribute__((address_space(1))) void*)(Bp + 32 * 1024 + (k0)), \
            (__attribute__((address_space(3))) void*)&sB[buf][2048 + tid * 8], 16, 0, 0); \
    } while (0)

    const int rb = w * 16 + l15;                  // B row (output col within tile)
    floatx4 acc[4] = {};

#define CMP6(buf)                                                               \
    do {                                                                        \
        _Pragma("unroll")                                                       \
        for (int ks = 0; ks < 2; ++ks) {                                        \
            const int kq = ks * 4 + lh;                                         \
            const short8 b_ = *reinterpret_cast<const short8*>(                 \
                &sB[buf][rb * 64 + ((kq ^ (rb & 7)) << 3)]);                    \
            __builtin_amdgcn_s_setprio(1);                                      \
            _Pragma("unroll")                                                   \
            for (int mi = 0; mi < 4; ++mi) {                                    \
                const int ra = mi * 16 + l15;                                   \
                const short8 a_ = *reinterpret_cast<const short8*>(             \
                    &sA[buf][ra * 64 + ((kq ^ (l15 & 7)) << 3)]);               \
                acc[mi] = __builtin_amdgcn_mfma_f32_16x16x32_bf16(              \
                    a_, b_, acc[mi], 0, 0, 0);                                  \
            }                                                                   \
            __builtin_amdgcn_s_setprio(0);                                      \
        }                                                                       \
    } while (0)

    STG6(0, 0);
    STG6(1, 64);
    for (int t3 = 0; t3 < 12; t3 += 3) {          // computes tiles 0..11, stages 2..13
        asm volatile("s_barrier" ::: "memory");
        STG6(2, (t3 + 2) * 64);
        asm volatile("s_waitcnt vmcnt(4)" ::: "memory");
        CMP6(0);
        asm volatile("s_barrier" ::: "memory");
        STG6(0, (t3 + 3) * 64);
        asm volatile("s_waitcnt vmcnt(4)" ::: "memory");
        CMP6(1);
        asm volatile("s_barrier" ::: "memory");
        STG6(1, (t3 + 4) * 64);
        asm volatile("s_waitcnt vmcnt(4)" ::: "memory");
        CMP6(2);
    }
    // t=12: stage tile14 (buf2), retire t12 (vmcnt(8): t13,t14 remain)
    asm volatile("s_barrier" ::: "memory");
    STG6(2, 14 * 64);
    asm volatile("s_waitcnt vmcnt(8)" ::: "memory");
    CMP6(0);
    // t=13: stage tile15 (buf0, its tile12 computed), retire t13
    asm volatile("s_barrier" ::: "memory");
    STG6(0, 15 * 64);
    asm volatile("s_waitcnt vmcnt(8)" ::: "memory");
    CMP6(1);
    // t=14: retire t14
    asm volatile("s_barrier" ::: "memory");
    asm volatile("s_waitcnt vmcnt(4)" ::: "memory");
    CMP6(2);
    // t=15: retire t15
    asm volatile("s_barrier" ::: "memory");
    asm volatile("s_waitcnt vmcnt(0)" ::: "memory");
    CMP6(0);
#undef CMP6
#undef STG6

    // epilogue: D col = lane&15 (-> n), row = lh*4+j (+mi*16) (-> m)
    const int n  = n0 + w * 16 + l15;
    const float bb = bias[n];
    #pragma unroll
    for (int mi = 0; mi < 4; ++mi) {
        #pragma unroll
        for (int j = 0; j < 4; ++j) {
            const int m = m0 + mi * 16 + lh * 4 + j;
            float v = fast_tanh(acc[mi][j] + bb);
            if (last) outf[(size_t)m * 512 + n] = v;
            else      outb[(size_t)m * 512 + n] = f2bf(v);
        }
    }
}

extern "C" void kernel_launch(void* const* d_in, const int* in_sizes, int n_in,
                              void* d_out, int out_size, void* d_ws, size_t ws_size,
                              hipStream_t stream) {
    const int*   ids  = (const int*)d_in[0];
    const float* emb  = (const float*)d_in[1];
    const float* W    = (const float*)d_in[2];
    const float* bias = (const float*)d_in[3];
    float* out = (float*)d_out;

    unsigned short* Wb = (unsigned short*)d_ws;        // 1 MiB
    unsigned short* hA = Wb + 524288;                  // 128 MiB region
    unsigned short* hB = hA + 67108864;                // 64 MiB region

    wconv<<<512, 256, 0, stream>>>((const float4*)W, (ushort4*)Wb);
    embed_tanh<<<32768, 256, 0, stream>>>(ids, emb, hA);

    int M = 65536;
    for (int l = 1; l <= 4; ++l) {                     // outputs: hB,hA,hB,hA
        const unsigned short* in = (l & 1) ? hA : hB;
        unsigned short*       ob = (l & 1) ? hB : hA;
        int gm = M / 128;
        level_gemm<<<gm * 4, 256, 0, stream>>>(in, Wb, bias, ob, M);
        M >>= 1;
    }
    // levels 5..11: Mout = 4096,2048,1024,512,256,128,64; grid = (Mout/64)*8
    for (int l = 5; l <= 11; ++l) {
        const unsigned short* in = (l & 1) ? hA : hB;
        unsigned short*       ob = (l & 1) ? hB : hA;
        small_gemm<<<(M / 64) * 8, 256, 0, stream>>>(in, Wb, bias, ob, out,
                                                     l == 11 ? 1 : 0);
        M >>= 1;
    }
}

// Round 13
// 291.989 us; speedup vs baseline: 1.5343x; 1.1436x over previous
//
#include <hip/hip_runtime.h>
#include <stdint.h>

typedef __attribute__((ext_vector_type(8))) short short8;
typedef __attribute__((ext_vector_type(4))) float floatx4;

__device__ __forceinline__ unsigned short f2bf(float x) {
    unsigned int u = __builtin_bit_cast(unsigned int, x);
    unsigned int r = (u + 0x7FFFu + ((u >> 16) & 1u)) >> 16;   // RNE
    return (unsigned short)r;
}

// tanh = (e^2x-1)/(e^2x+1), clamp |x|<=10; rcp + 1 Newton. ~1e-7 rel err.
__device__ __forceinline__ float fast_tanh(float x) {
    float xc = fminf(fmaxf(x, -10.0f), 10.0f);
    float e  = __expf(2.0f * xc);
    float d  = e + 1.0f;
    float r  = __builtin_amdgcn_rcpf(d);
    r = r * (2.0f - d * r);
    return (e - 1.0f) * r;
}

// ---- W f32 -> bf16 ----
__global__ void wconv(const float4* __restrict__ W4, ushort4* __restrict__ Wb4) {
    int i = blockIdx.x * 256 + threadIdx.x;
    float4 v = W4[i];
    ushort4 o;
    o.x = f2bf(v.x); o.y = f2bf(v.y); o.z = f2bf(v.z); o.w = f2bf(v.w);
    Wb4[i] = o;
}

// ---- vocab table: embT[v][c] = bf16(tanh(emb[v][c])), 32000x512 (32 MB) ----
// Replaces the per-leaf embed pass: 131072 gathered rows -> 32000 table rows.
__global__ void tconv(const float4* __restrict__ emb4, ushort4* __restrict__ embT4) {
    int i = blockIdx.x * 256 + threadIdx.x;   // 4,096,000 threads exactly
    float4 v = emb4[i];
    ushort4 o;
    o.x = f2bf(fast_tanh(v.x)); o.y = f2bf(fast_tanh(v.y));
    o.z = f2bf(fast_tanh(v.z)); o.w = f2bf(fast_tanh(v.w));
    embT4[i] = o;
}

// ======== shared GEMM-core macros (validated rounds 3-12) ========
#define STAGE_(sA, sB, Ap, Bp, buf, k0)                                         \
    do {                                                                        \
        __builtin_amdgcn_global_load_lds(                                       \
            (const __attribute__((address_space(1))) void*)((Ap) + (k0)),       \
            (__attribute__((address_space(3))) void*)&sA[buf][tid * 8], 16, 0, 0); \
        __builtin_amdgcn_global_load_lds(                                       \
            (const __attribute__((address_space(1))) void*)((Ap) + 64 * 1024 + (k0)), \
            (__attribute__((address_space(3))) void*)&sA[buf][2048 + tid * 8], 16, 0, 0); \
        __builtin_amdgcn_global_load_lds(                                       \
            (const __attribute__((address_space(1))) void*)((Bp) + (k0)),       \
            (__attribute__((address_space(3))) void*)&sB[buf][tid * 8], 16, 0, 0); \
        __builtin_amdgcn_global_load_lds(                                       \
            (const __attribute__((address_space(1))) void*)((Bp) + 64 * 1024 + (k0)), \
            (__attribute__((address_space(3))) void*)&sB[buf][2048 + tid * 8], 16, 0, 0); \
    } while (0)

// level-1 staging: A gathered from embT via leaf ids (per-lane global src).
// Row r content: col c in [0,512) -> embT[ids[2r]][c]; c in [512,1024) ->
// embT[ids[2r+1]][c-512]. k0 multiple of 32 + swcol<32 never straddles 512.
#define STAGE_E(sA, sB, buf, k0)                                                \
    do {                                                                        \
        const ushort* sLo_ = ((k0) < 512) ? (a0lo + (k0)) : (a1lo + ((k0) - 512)); \
        const ushort* sHi_ = ((k0) < 512) ? (a0hi + (k0)) : (a1hi + ((k0) - 512)); \
        __builtin_amdgcn_global_load_lds(                                       \
            (const __attribute__((address_space(1))) void*)sLo_,                \
            (__attribute__((address_space(3))) void*)&sA[buf][tid * 8], 16, 0, 0); \
        __builtin_amdgcn_global_load_lds(                                       \
            (const __attribute__((address_space(1))) void*)sHi_,                \
            (__attribute__((address_space(3))) void*)&sA[buf][2048 + tid * 8], 16, 0, 0); \
        __builtin_amdgcn_global_load_lds(                                       \
            (const __attribute__((address_space(1))) void*)(Bp + (k0)),         \
            (__attribute__((address_space(3))) void*)&sB[buf][tid * 8], 16, 0, 0); \
        __builtin_amdgcn_global_load_lds(                                       \
            (const __attribute__((address_space(1))) void*)(Bp + 64 * 1024 + (k0)), \
            (__attribute__((address_space(3))) void*)&sB[buf][2048 + tid * 8], 16, 0, 0); \
    } while (0)

#define COMPUTE_(sA, sB, cur)                                                   \
    do {                                                                        \
        short8 a_[4], b_[4];                                                    \
        _Pragma("unroll")                                                       \
        for (int mi = 0; mi < 4; ++mi)                                          \
            a_[mi] = *reinterpret_cast<const short8*>(&sA[cur][(rA + mi * 16) * 32 + kksw]); \
        _Pragma("unroll")                                                       \
        for (int ni = 0; ni < 4; ++ni)                                          \
            b_[ni] = *reinterpret_cast<const short8*>(&sB[cur][(rB + ni * 16) * 32 + kksw]); \
        __builtin_amdgcn_s_setprio(1);                                          \
        _Pragma("unroll")                                                       \
        for (int mi = 0; mi < 4; ++mi)                                          \
            _Pragma("unroll")                                                   \
            for (int ni = 0; ni < 4; ++ni)                                      \
                acc[mi][ni] = __builtin_amdgcn_mfma_f32_16x16x32_bf16(          \
                    a_[mi], b_[ni], acc[mi][ni], 0, 0, 0);                      \
        __builtin_amdgcn_s_setprio(0);                                          \
    } while (0)

// K-loop parameterized on the stage macro call (STG bound to (buf,k0)).
#define KLOOPX_(STG, sA, sB)                                                    \
    do {                                                                        \
        STG(0, 0);                                                              \
        STG(1, 32);                                                             \
        for (int t = 0; t < 30; t += 3) {                                       \
            asm volatile("s_barrier" ::: "memory");                             \
            STG(2, (t + 2) * 32);                                               \
            asm volatile("s_waitcnt vmcnt(4)" ::: "memory");                    \
            COMPUTE_(sA, sB, 0);                                                \
            asm volatile("s_barrier" ::: "memory");                             \
            STG(0, (t + 3) * 32);                                               \
            asm volatile("s_waitcnt vmcnt(4)" ::: "memory");                    \
            COMPUTE_(sA, sB, 1);                                                \
            asm volatile("s_barrier" ::: "memory");                             \
            STG(1, (t + 4) * 32);                                               \
            asm volatile("s_waitcnt vmcnt(4)" ::: "memory");                    \
            COMPUTE_(sA, sB, 2);                                                \
        }                                                                       \
        asm volatile("s_barrier" ::: "memory");                                 \
        asm volatile("s_waitcnt vmcnt(0)" ::: "memory");                        \
        COMPUTE_(sA, sB, 0);                                                    \
        asm volatile("s_barrier" ::: "memory");                                 \
        asm volatile("s_waitcnt vmcnt(0)" ::: "memory");                        \
        COMPUTE_(sA, sB, 1);                                                    \
    } while (0)

#define EPILOGUE_B()                                                            \
    do {                                                                        \
        const int mrow = (lane >> 4) * 4;                                       \
        const int ncol = lane & 15;                                             \
        _Pragma("unroll")                                                       \
        for (int mi = 0; mi < 4; ++mi) {                                        \
            _Pragma("unroll")                                                   \
            for (int ni = 0; ni < 4; ++ni) {                                    \
                const int n = n0 + wc * 64 + ni * 16 + ncol;                    \
                const float bb = bias[n];                                       \
                _Pragma("unroll")                                               \
                for (int j = 0; j < 4; ++j) {                                   \
                    const int m = m0 + wr * 64 + mi * 16 + mrow + j;            \
                    float v = fast_tanh(acc[mi][ni][j] + bb);                   \
                    outb[(size_t)m * 512 + n] = f2bf(v);                        \
                }                                                               \
            }                                                                   \
        }                                                                       \
    } while (0)

// ---- level 1 (fused embed): out[65536][512] = tanh(A @ W^T + b),
// A[m] = concat(embT[ids[2m]], embT[ids[2m+1]]) gathered during staging ----
__global__ __launch_bounds__(256)
void level1_gemm(const int* __restrict__ ids, const ushort* __restrict__ embT,
                 const ushort* __restrict__ Bt, const float* __restrict__ bias,
                 ushort* __restrict__ outb)
{
    const int nb  = gridDim.x;
    int bid = blockIdx.x;
    const int per = nb >> 3;
    const int lin = (bid & 7) * per + (bid >> 3);  // bijective XCD chunking
    const int mt = lin >> 2, nt = lin & 3;
    const int m0 = mt * 128, n0 = nt * 128;

    __shared__ alignas(16) ushort sA[3][4096];
    __shared__ alignas(16) ushort sB[3][4096];

    const int tid  = threadIdx.x;
    const int lane = tid & 63;
    const int w    = tid >> 6;
    const int wr   = w >> 1, wc = w & 1;

    const int sr    = tid >> 2;
    const int swcol = (((tid & 3) ^ ((tid >> 3) & 3)) << 3);
    const int mlo = m0 + sr, mhi = m0 + sr + 64;
    const ushort* a0lo = embT + (size_t)ids[2 * mlo]     * 512 + swcol;
    const ushort* a1lo = embT + (size_t)ids[2 * mlo + 1] * 512 + swcol;
    const ushort* a0hi = embT + (size_t)ids[2 * mhi]     * 512 + swcol;
    const ushort* a1hi = embT + (size_t)ids[2 * mhi + 1] * 512 + swcol;
    const ushort* Bp   = Bt + (size_t)(n0 + sr) * 1024 + swcol;

    const int rA   = wr * 64 + (lane & 15);
    const int rB   = wc * 64 + (lane & 15);
    const int kksw = (((lane >> 4) ^ ((lane >> 1) & 3)) << 3);

    floatx4 acc[4][4] = {};
#define STG1(buf, k0) STAGE_E(sA, sB, buf, k0)
    KLOOPX_(STG1, sA, sB);
#undef STG1
    EPILOGUE_B();
}

// ---- levels 2..4: out[M][512] = tanh(A[M][1024] @ W^T + b) ----
__global__ __launch_bounds__(256)
void level_gemm(const ushort* __restrict__ A, const ushort* __restrict__ Bt,
                const float* __restrict__ bias,
                ushort* __restrict__ outb, int M)
{
    const int nb  = gridDim.x;
    int bid = blockIdx.x;
    const int per = nb >> 3;
    const int lin = (bid & 7) * per + (bid >> 3);
    const int mt = lin >> 2, nt = lin & 3;
    const int m0 = mt * 128, n0 = nt * 128;

    __shared__ alignas(16) ushort sA[3][4096];
    __shared__ alignas(16) ushort sB[3][4096];

    const int tid  = threadIdx.x;
    const int lane = tid & 63;
    const int w    = tid >> 6;
    const int wr   = w >> 1, wc = w & 1;

    const int sr    = tid >> 2;
    const int swcol = (((tid & 3) ^ ((tid >> 3) & 3)) << 3);
    const ushort* Ap = A  + (size_t)(m0 + sr) * 1024 + swcol;
    const ushort* Bp = Bt + (size_t)(n0 + sr) * 1024 + swcol;

    const int rA   = wr * 64 + (lane & 15);
    const int rB   = wc * 64 + (lane & 15);
    const int kksw = (((lane >> 4) ^ ((lane >> 1) & 3)) << 3);

    floatx4 acc[4][4] = {};
#define STG0(buf, k0) STAGE_(sA, sB, Ap, Bp, buf, k0)
    KLOOPX_(STG0, sA, sB);
#undef STG0
    EPILOGUE_B();
}

// ---- levels 5..11: 64x64-tile GEMM, grid = (Mout/64) x 8 N-slices ----
// (validated round 12: spreads W over 8x more CUs; BK=64, 3 bufs, vmcnt(4))
__global__ __launch_bounds__(256)
void small_gemm(const ushort* __restrict__ A, const ushort* __restrict__ Bt,
                const float* __restrict__ bias,
                ushort* __restrict__ outb, float* __restrict__ outf, int last)
{
    __shared__ alignas(16) ushort sA[3][4096];   // [buf][64 rows x 64 elems]
    __shared__ alignas(16) ushort sB[3][4096];

    const int tid  = threadIdx.x;
    const int lane = tid & 63;
    const int w    = tid >> 6;
    const int l15  = lane & 15;
    const int lh   = lane >> 4;
    const int mt   = blockIdx.x >> 3, nt = blockIdx.x & 7;
    const int m0   = mt * 64, n0 = nt * 64;

    const int r0 = tid >> 3;
    const int s0 = tid & 7;
    const int swz = ((s0 ^ (r0 & 7)) << 3);
    const ushort* Ap = A  + (size_t)(m0 + r0) * 1024 + swz;
    const ushort* Bp = Bt + (size_t)(n0 + r0) * 1024 + swz;

#define STG6(buf, k0)                                                           \
    do {                                                                        \
        __builtin_amdgcn_global_load_lds(                                       \
            (const __attribute__((address_space(1))) void*)(Ap + (k0)),         \
            (__attribute__((address_space(3))) void*)&sA[buf][tid * 8], 16, 0, 0); \
        __builtin_amdgcn_global_load_lds(                                       \
            (const __attribute__((address_space(1))) void*)(Ap + 32 * 1024 + (k0)), \
            (__attribute__((address_space(3))) void*)&sA[buf][2048 + tid * 8], 16, 0, 0); \
        __builtin_amdgcn_global_load_lds(                                       \
            (const __attribute__((address_space(1))) void*)(Bp + (k0)),         \
            (__attribute__((address_space(3))) void*)&sB[buf][tid * 8], 16, 0, 0); \
        __builtin_amdgcn_global_load_lds(                                       \
            (const __attribute__((address_space(1))) void*)(Bp + 32 * 1024 + (k0)), \
            (__attribute__((address_space(3))) void*)&sB[buf][2048 + tid * 8], 16, 0, 0); \
    } while (0)

    const int rb = w * 16 + l15;
    floatx4 acc[4] = {};

#define CMP6(buf)                                                               \
    do {                                                                        \
        _Pragma("unroll")                                                       \
        for (int ks = 0; ks < 2; ++ks) {                                        \
            const int kq = ks * 4 + lh;                                         \
            const short8 b_ = *reinterpret_cast<const short8*>(                 \
                &sB[buf][rb * 64 + ((kq ^ (rb & 7)) << 3)]);                    \
            __builtin_amdgcn_s_setprio(1);                                      \
            _Pragma("unroll")                                                   \
            for (int mi = 0; mi < 4; ++mi) {                                    \
                const int ra = mi * 16 + l15;                                   \
                const short8 a_ = *reinterpret_cast<const short8*>(             \
                    &sA[buf][ra * 64 + ((kq ^ (l15 & 7)) << 3)]);               \
                acc[mi] = __builtin_amdgcn_mfma_f32_16x16x32_bf16(              \
                    a_, b_, acc[mi], 0, 0, 0);                                  \
            }                                                                   \
            __builtin_amdgcn_s_setprio(0);                                      \
        }                                                                       \
    } while (0)

    STG6(0, 0);
    STG6(1, 64);
    for (int t3 = 0; t3 < 12; t3 += 3) {
        asm volatile("s_barrier" ::: "memory");
        STG6(2, (t3 + 2) * 64);
        asm volatile("s_waitcnt vmcnt(4)" ::: "memory");
        CMP6(0);
        asm volatile("s_barrier" ::: "memory");
        STG6(0, (t3 + 3) * 64);
        asm volatile("s_waitcnt vmcnt(4)" ::: "memory");
        CMP6(1);
        asm volatile("s_barrier" ::: "memory");
        STG6(1, (t3 + 4) * 64);
        asm volatile("s_waitcnt vmcnt(4)" ::: "memory");
        CMP6(2);
    }
    asm volatile("s_barrier" ::: "memory");
    STG6(2, 14 * 64);
    asm volatile("s_waitcnt vmcnt(8)" ::: "memory");
    CMP6(0);
    asm volatile("s_barrier" ::: "memory");
    STG6(0, 15 * 64);
    asm volatile("s_waitcnt vmcnt(8)" ::: "memory");
    CMP6(1);
    asm volatile("s_barrier" ::: "memory");
    asm volatile("s_waitcnt vmcnt(4)" ::: "memory");
    CMP6(2);
    asm volatile("s_barrier" ::: "memory");
    asm volatile("s_waitcnt vmcnt(0)" ::: "memory");
    CMP6(0);
#undef CMP6
#undef STG6

    const int n  = n0 + w * 16 + l15;
    const float bb = bias[n];
    #pragma unroll
    for (int mi = 0; mi < 4; ++mi) {
        #pragma unroll
        for (int j = 0; j < 4; ++j) {
            const int m = m0 + mi * 16 + lh * 4 + j;
            float v = fast_tanh(acc[mi][j] + bb);
            if (last) outf[(size_t)m * 512 + n] = v;
            else      outb[(size_t)m * 512 + n] = f2bf(v);
        }
    }
}

extern "C" void kernel_launch(void* const* d_in, const int* in_sizes, int n_in,
                              void* d_out, int out_size, void* d_ws, size_t ws_size,
                              hipStream_t stream) {
    const int*   ids  = (const int*)d_in[0];
    const float* emb  = (const float*)d_in[1];
    const float* W    = (const float*)d_in[2];
    const float* bias = (const float*)d_in[3];
    float* out = (float*)d_out;

    // ws: Wb 1MiB | embT 32MB (tanh'd vocab) | hB 64MiB | hA 32MiB  (~128 MiB)
    unsigned short* Wb   = (unsigned short*)d_ws;
    unsigned short* embT = Wb + 524288;
    unsigned short* hB   = embT + 16384000;
    unsigned short* hA   = hB + 33554432;

    wconv<<<512, 256, 0, stream>>>((const float4*)W, (ushort4*)Wb);
    tconv<<<16000, 256, 0, stream>>>((const float4*)emb, (ushort4*)embT);

    // level 1: fused gather-GEMM, M=65536 -> writes hB
    level1_gemm<<<2048, 256, 0, stream>>>(ids, embT, Wb, bias, hB);

    int M = 32768;
    for (int l = 2; l <= 4; ++l) {                 // in: hB,hA,hB -> out: hA,hB,hA
        const unsigned short* in = (l & 1) ? hA : hB;
        unsigned short*       ob = (l & 1) ? hB : hA;
        level_gemm<<<(M / 128) * 4, 256, 0, stream>>>(in, Wb, bias, ob, M);
        M >>= 1;
    }
    // levels 5..11: Mout = 4096..64; grid = (Mout/64)*8
    for (int l = 5; l <= 11; ++l) {
        const unsigned short* in = (l & 1) ? hA : hB;
        unsigned short*       ob = (l & 1) ? hB : hA;
        small_gemm<<<(M / 64) * 8, 256, 0, stream>>>(in, Wb, bias, ob, out,
                                                     l == 11 ? 1 : 0);
        M >>= 1;
    }
}

// Round 14
// 274.209 us; speedup vs baseline: 1.6338x; 1.0648x over previous
//
#include <hip/hip_runtime.h>
#include <stdint.h>

typedef __attribute__((ext_vector_type(8))) short short8;
typedef __attribute__((ext_vector_type(4))) float floatx4;

__device__ __forceinline__ unsigned short f2bf(float x) {
    unsigned int u = __builtin_bit_cast(unsigned int, x);
    unsigned int r = (u + 0x7FFFu + ((u >> 16) & 1u)) >> 16;   // RNE
    return (unsigned short)r;
}
__device__ __forceinline__ float bf2f(unsigned short x) {
    unsigned int u = ((unsigned int)x) << 16;
    return __builtin_bit_cast(float, u);
}

// tanh = (e^2x-1)/(e^2x+1), clamp |x|<=10; rcp + 1 Newton. ~1e-7 rel err.
__device__ __forceinline__ float fast_tanh(float x) {
    float xc = fminf(fmaxf(x, -10.0f), 10.0f);
    float e  = __expf(2.0f * xc);
    float d  = e + 1.0f;
    float r  = __builtin_amdgcn_rcpf(d);
    r = r * (2.0f - d * r);
    return (e - 1.0f) * r;
}

// ---- W f32 -> bf16 ----
__global__ void wconv(const float4* __restrict__ W4, ushort4* __restrict__ Wb4) {
    int i = blockIdx.x * 256 + threadIdx.x;
    float4 v = W4[i];
    ushort4 o;
    o.x = f2bf(v.x); o.y = f2bf(v.y); o.z = f2bf(v.z); o.w = f2bf(v.w);
    Wb4[i] = o;
}

// ---- vocab table: embT[v][c] = bf16(tanh(emb[v][c])), 32000x512 ----
__global__ void tconv(const float4* __restrict__ emb4, ushort4* __restrict__ embT4) {
    int i = blockIdx.x * 256 + threadIdx.x;   // 4,096,000 threads exactly
    float4 v = emb4[i];
    ushort4 o;
    o.x = f2bf(fast_tanh(v.x)); o.y = f2bf(fast_tanh(v.y));
    o.z = f2bf(fast_tanh(v.z)); o.w = f2bf(fast_tanh(v.w));
    embT4[i] = o;
}

// ======== shared GEMM-core macros (validated rounds 3-13) ========
#define STAGE_(sA, sB, Ap, Bp, buf, k0)                                         \
    do {                                                                        \
        __builtin_amdgcn_global_load_lds(                                       \
            (const __attribute__((address_space(1))) void*)((Ap) + (k0)),       \
            (__attribute__((address_space(3))) void*)&sA[buf][tid * 8], 16, 0, 0); \
        __builtin_amdgcn_global_load_lds(                                       \
            (const __attribute__((address_space(1))) void*)((Ap) + 64 * 1024 + (k0)), \
            (__attribute__((address_space(3))) void*)&sA[buf][2048 + tid * 8], 16, 0, 0); \
        __builtin_amdgcn_global_load_lds(                                       \
            (const __attribute__((address_space(1))) void*)((Bp) + (k0)),       \
            (__attribute__((address_space(3))) void*)&sB[buf][tid * 8], 16, 0, 0); \
        __builtin_amdgcn_global_load_lds(                                       \
            (const __attribute__((address_space(1))) void*)((Bp) + 64 * 1024 + (k0)), \
            (__attribute__((address_space(3))) void*)&sB[buf][2048 + tid * 8], 16, 0, 0); \
    } while (0)

// pq variant: A stride 512 (embT), B stride 1024 (W row) — same LDS layout.
#define STAGE_PQ(sA, sB, Ap, Bp, buf, k0)                                       \
    do {                                                                        \
        __builtin_amdgcn_global_load_lds(                                       \
            (const __attribute__((address_space(1))) void*)((Ap) + (k0)),       \
            (__attribute__((address_space(3))) void*)&sA[buf][tid * 8], 16, 0, 0); \
        __builtin_amdgcn_global_load_lds(                                       \
            (const __attribute__((address_space(1))) void*)((Ap) + 64 * 512 + (k0)), \
            (__attribute__((address_space(3))) void*)&sA[buf][2048 + tid * 8], 16, 0, 0); \
        __builtin_amdgcn_global_load_lds(                                       \
            (const __attribute__((address_space(1))) void*)((Bp) + (k0)),       \
            (__attribute__((address_space(3))) void*)&sB[buf][tid * 8], 16, 0, 0); \
        __builtin_amdgcn_global_load_lds(                                       \
            (const __attribute__((address_space(1))) void*)((Bp) + 64 * 1024 + (k0)), \
            (__attribute__((address_space(3))) void*)&sB[buf][2048 + tid * 8], 16, 0, 0); \
    } while (0)

#define COMPUTE_(sA, sB, cur)                                                   \
    do {                                                                        \
        short8 a_[4], b_[4];                                                    \
        _Pragma("unroll")                                                       \
        for (int mi = 0; mi < 4; ++mi)                                          \
            a_[mi] = *reinterpret_cast<const short8*>(&sA[cur][(rA + mi * 16) * 32 + kksw]); \
        _Pragma("unroll")                                                       \
        for (int ni = 0; ni < 4; ++ni)                                          \
            b_[ni] = *reinterpret_cast<const short8*>(&sB[cur][(rB + ni * 16) * 32 + kksw]); \
        __builtin_amdgcn_s_setprio(1);                                          \
        _Pragma("unroll")                                                       \
        for (int mi = 0; mi < 4; ++mi)                                          \
            _Pragma("unroll")                                                   \
            for (int ni = 0; ni < 4; ++ni)                                      \
                acc[mi][ni] = __builtin_amdgcn_mfma_f32_16x16x32_bf16(          \
                    a_[mi], b_[ni], acc[mi][ni], 0, 0, 0);                      \
        __builtin_amdgcn_s_setprio(0);                                          \
    } while (0)

#define ITER_S_(STG, sA, sB, cur, stg, tile)                                    \
    do {                                                                        \
        asm volatile("s_barrier" ::: "memory");                                 \
        STG(sA, sB, Ap, Bp, stg, (tile) * 32);                                  \
        asm volatile("s_waitcnt vmcnt(4)" ::: "memory");                        \
        COMPUTE_(sA, sB, cur);                                                  \
    } while (0)

#define ITER_D_(sA, sB, cur)                                                    \
    do {                                                                        \
        asm volatile("s_barrier" ::: "memory");                                 \
        asm volatile("s_waitcnt vmcnt(0)" ::: "memory");                        \
        COMPUTE_(sA, sB, cur);                                                  \
    } while (0)

// ---- P/Q tables: PQ[t][v][n] = embT[v] . W[n][t*512 .. t*512+512)  (bf16)
// M=32000 (=250x128 exact), K=512 (16 BK=32 tiles), grid 2000 = 2x250x4.
__global__ __launch_bounds__(256)
void pq_gemm(const ushort* __restrict__ embT, const ushort* __restrict__ Bt,
             ushort* __restrict__ PQ)
{
    const int nb  = gridDim.x;                     // 2000
    int bid = blockIdx.x;
    const int per = nb >> 3;                       // 250
    const int lin = (bid & 7) * per + (bid >> 3);  // bijective XCD chunking
    const int table = lin / 1000;
    const int rem   = lin - table * 1000;
    const int mt = rem >> 2, nt = rem & 3;
    const int m0 = mt * 128, n0 = nt * 128;

    __shared__ alignas(16) ushort sA[3][4096];
    __shared__ alignas(16) ushort sB[3][4096];

    const int tid  = threadIdx.x;
    const int lane = tid & 63;
    const int w    = tid >> 6;
    const int wr   = w >> 1, wc = w & 1;

    const int sr    = tid >> 2;
    const int swcol = (((tid & 3) ^ ((tid >> 3) & 3)) << 3);
    const ushort* Ap = embT + (size_t)(m0 + sr) * 512 + swcol;
    const ushort* Bp = Bt + (size_t)(n0 + sr) * 1024 + (table << 9) + swcol;

    const int rA   = wr * 64 + (lane & 15);
    const int rB   = wc * 64 + (lane & 15);
    const int kksw = (((lane >> 4) ^ ((lane >> 1) & 3)) << 3);

    floatx4 acc[4][4] = {};

    // 16 K-tiles: stage 0,1; staged-iters t=0..13; drains t=14,15.
    STAGE_PQ(sA, sB, Ap, Bp, 0, 0);
    STAGE_PQ(sA, sB, Ap, Bp, 1, 32);
    for (int t = 0; t < 12; t += 3) {
        ITER_S_(STAGE_PQ, sA, sB, 0, 2, t + 2);
        ITER_S_(STAGE_PQ, sA, sB, 1, 0, t + 3);
        ITER_S_(STAGE_PQ, sA, sB, 2, 1, t + 4);
    }
    ITER_S_(STAGE_PQ, sA, sB, 0, 2, 14);   // t=12
    ITER_S_(STAGE_PQ, sA, sB, 1, 0, 15);   // t=13
    ITER_D_(sA, sB, 2);                    // t=14
    ITER_D_(sA, sB, 0);                    // t=15

    ushort* outp = PQ + (size_t)table * 16384000;
    const int mrow = (lane >> 4) * 4;
    const int ncol = lane & 15;
    #pragma unroll
    for (int mi = 0; mi < 4; ++mi)
        #pragma unroll
        for (int ni = 0; ni < 4; ++ni) {
            const int n = n0 + wc * 64 + ni * 16 + ncol;
            #pragma unroll
            for (int j = 0; j < 4; ++j) {
                const int m = m0 + wr * 64 + mi * 16 + mrow + j;
                outp[(size_t)m * 512 + n] = f2bf(acc[mi][ni][j]);
            }
        }
}

// ---- level 1 via tables: h1[m] = tanh(P[idL] + Q[idR] + b), 65536x512 bf16 ----
__global__ void lvl1_add(const int* __restrict__ ids, const ushort* __restrict__ PQ,
                         const float* __restrict__ bias, ushort* __restrict__ h1)
{
    int idx = blockIdx.x * 256 + threadIdx.x;   // 4,194,304 threads
    int m = idx >> 6;
    int c = (idx & 63) << 3;
    const int il = ids[2 * m], ir = ids[2 * m + 1];
    const short8 p = *reinterpret_cast<const short8*>(PQ + (size_t)il * 512 + c);
    const short8 q = *reinterpret_cast<const short8*>(PQ + 16384000 + (size_t)ir * 512 + c);
    const float4 b0 = *reinterpret_cast<const float4*>(bias + c);
    const float4 b1 = *reinterpret_cast<const float4*>(bias + c + 4);
    short8 o;
    o[0] = (short)f2bf(fast_tanh(bf2f((unsigned short)p[0]) + bf2f((unsigned short)q[0]) + b0.x));
    o[1] = (short)f2bf(fast_tanh(bf2f((unsigned short)p[1]) + bf2f((unsigned short)q[1]) + b0.y));
    o[2] = (short)f2bf(fast_tanh(bf2f((unsigned short)p[2]) + bf2f((unsigned short)q[2]) + b0.z));
    o[3] = (short)f2bf(fast_tanh(bf2f((unsigned short)p[3]) + bf2f((unsigned short)q[3]) + b0.w));
    o[4] = (short)f2bf(fast_tanh(bf2f((unsigned short)p[4]) + bf2f((unsigned short)q[4]) + b1.x));
    o[5] = (short)f2bf(fast_tanh(bf2f((unsigned short)p[5]) + bf2f((unsigned short)q[5]) + b1.y));
    o[6] = (short)f2bf(fast_tanh(bf2f((unsigned short)p[6]) + bf2f((unsigned short)q[6]) + b1.z));
    o[7] = (short)f2bf(fast_tanh(bf2f((unsigned short)p[7]) + bf2f((unsigned short)q[7]) + b1.w));
    *reinterpret_cast<short8*>(h1 + (size_t)idx * 8) = o;
}

// ---- levels 2..4: out[M][512] = tanh(A[M][1024] @ W^T + b) ----
__global__ __launch_bounds__(256)
void level_gemm(const ushort* __restrict__ A, const ushort* __restrict__ Bt,
                const float* __restrict__ bias,
                ushort* __restrict__ outb, int M)
{
    const int nb  = gridDim.x;
    int bid = blockIdx.x;
    const int per = nb >> 3;
    const int lin = (bid & 7) * per + (bid >> 3);
    const int mt = lin >> 2, nt = lin & 3;
    const int m0 = mt * 128, n0 = nt * 128;

    __shared__ alignas(16) ushort sA[3][4096];
    __shared__ alignas(16) ushort sB[3][4096];

    const int tid  = threadIdx.x;
    const int lane = tid & 63;
    const int w    = tid >> 6;
    const int wr   = w >> 1, wc = w & 1;

    const int sr    = tid >> 2;
    const int swcol = (((tid & 3) ^ ((tid >> 3) & 3)) << 3);
    const ushort* Ap = A  + (size_t)(m0 + sr) * 1024 + swcol;
    const ushort* Bp = Bt + (size_t)(n0 + sr) * 1024 + swcol;

    const int rA   = wr * 64 + (lane & 15);
    const int rB   = wc * 64 + (lane & 15);
    const int kksw = (((lane >> 4) ^ ((lane >> 1) & 3)) << 3);

    floatx4 acc[4][4] = {};

    STAGE_(sA, sB, Ap, Bp, 0, 0);
    STAGE_(sA, sB, Ap, Bp, 1, 32);
    for (int t = 0; t < 30; t += 3) {
        ITER_S_(STAGE_, sA, sB, 0, 2, t + 2);
        ITER_S_(STAGE_, sA, sB, 1, 0, t + 3);
        ITER_S_(STAGE_, sA, sB, 2, 1, t + 4);
    }
    ITER_D_(sA, sB, 0);
    ITER_D_(sA, sB, 1);

    const int mrow = (lane >> 4) * 4;
    const int ncol = lane & 15;
    #pragma unroll
    for (int mi = 0; mi < 4; ++mi)
        #pragma unroll
        for (int ni = 0; ni < 4; ++ni) {
            const int n = n0 + wc * 64 + ni * 16 + ncol;
            const float bb = bias[n];
            #pragma unroll
            for (int j = 0; j < 4; ++j) {
                const int m = m0 + wr * 64 + mi * 16 + mrow + j;
                float v = fast_tanh(acc[mi][ni][j] + bb);
                outb[(size_t)m * 512 + n] = f2bf(v);
            }
        }
}

// ---- levels 5..11: 64x64-tile GEMM, grid = (Mout/64) x 8 N-slices ----
__global__ __launch_bounds__(256)
void small_gemm(const ushort* __restrict__ A, const ushort* __restrict__ Bt,
                const float* __restrict__ bias,
                ushort* __restrict__ outb, float* __restrict__ outf, int last)
{
    __shared__ alignas(16) ushort sA[3][4096];
    __shared__ alignas(16) ushort sB[3][4096];

    const int tid  = threadIdx.x;
    const int lane = tid & 63;
    const int w    = tid >> 6;
    const int l15  = lane & 15;
    const int lh   = lane >> 4;
    const int mt   = blockIdx.x >> 3, nt = blockIdx.x & 7;
    const int m0   = mt * 64, n0 = nt * 64;

    const int r0 = tid >> 3;
    const int s0 = tid & 7;
    const int swz = ((s0 ^ (r0 & 7)) << 3);
    const ushort* Ap = A  + (size_t)(m0 + r0) * 1024 + swz;
    const ushort* Bp = Bt + (size_t)(n0 + r0) * 1024 + swz;

#define STG6(buf, k0)                                                           \
    do {                                                                        \
        __builtin_amdgcn_global_load_lds(                                       \
            (const __attribute__((address_space(1))) void*)(Ap + (k0)),         \
            (__attribute__((address_space(3))) void*)&sA[buf][tid * 8], 16, 0, 0); \
        __builtin_amdgcn_global_load_lds(                                       \
            (const __attribute__((address_space(1))) void*)(Ap + 32 * 1024 + (k0)), \
            (__attribute__((address_space(3))) void*)&sA[buf][2048 + tid * 8], 16, 0, 0); \
        __builtin_amdgcn_global_load_lds(                                       \
            (const __attribute__((address_space(1))) void*)(Bp + (k0)),         \
            (__attribute__((address_space(3))) void*)&sB[buf][tid * 8], 16, 0, 0); \
        __builtin_amdgcn_global_load_lds(                                       \
            (const __attribute__((address_space(1))) void*)(Bp + 32 * 1024 + (k0)), \
            (__attribute__((address_space(3))) void*)&sB[buf][2048 + tid * 8], 16, 0, 0); \
    } while (0)

    const int rb = w * 16 + l15;
    floatx4 acc[4] = {};

#define CMP6(buf)                                                               \
    do {                                                                        \
        _Pragma("unroll")                                                       \
        for (int ks = 0; ks < 2; ++ks) {                                        \
            const int kq = ks * 4 + lh;                                         \
            const short8 b_ = *reinterpret_cast<const short8*>(                 \
                &sB[buf][rb * 64 + ((kq ^ (rb & 7)) << 3)]);                    \
            __builtin_amdgcn_s_setprio(1);                                      \
            _Pragma("unroll")                                                   \
            for (int mi = 0; mi < 4; ++mi) {                                    \
                const int ra = mi * 16 + l15;                                   \
                const short8 a_ = *reinterpret_cast<const short8*>(             \
                    &sA[buf][ra * 64 + ((kq ^ (l15 & 7)) << 3)]);               \
                acc[mi] = __builtin_amdgcn_mfma_f32_16x16x32_bf16(              \
                    a_, b_, acc[mi], 0, 0, 0);                                  \
            }                                                                   \
            __builtin_amdgcn_s_setprio(0);                                      \
        }                                                                       \
    } while (0)

    STG6(0, 0);
    STG6(1, 64);
    for (int t3 = 0; t3 < 12; t3 += 3) {
        asm volatile("s_barrier" ::: "memory");
        STG6(2, (t3 + 2) * 64);
        asm volatile("s_waitcnt vmcnt(4)" ::: "memory");
        CMP6(0);
        asm volatile("s_barrier" ::: "memory");
        STG6(0, (t3 + 3) * 64);
        asm volatile("s_waitcnt vmcnt(4)" ::: "memory");
        CMP6(1);
        asm volatile("s_barrier" ::: "memory");
        STG6(1, (t3 + 4) * 64);
        asm volatile("s_waitcnt vmcnt(4)" ::: "memory");
        CMP6(2);
    }
    asm volatile("s_barrier" ::: "memory");
    STG6(2, 14 * 64);
    asm volatile("s_waitcnt vmcnt(8)" ::: "memory");
    CMP6(0);
    asm volatile("s_barrier" ::: "memory");
    STG6(0, 15 * 64);
    asm volatile("s_waitcnt vmcnt(8)" ::: "memory");
    CMP6(1);
    asm volatile("s_barrier" ::: "memory");
    asm volatile("s_waitcnt vmcnt(4)" ::: "memory");
    CMP6(2);
    asm volatile("s_barrier" ::: "memory");
    asm volatile("s_waitcnt vmcnt(0)" ::: "memory");
    CMP6(0);
#undef CMP6
#undef STG6

    const int n  = n0 + w * 16 + l15;
    const float bb = bias[n];
    #pragma unroll
    for (int mi = 0; mi < 4; ++mi) {
        #pragma unroll
        for (int j = 0; j < 4; ++j) {
            const int m = m0 + mi * 16 + lh * 4 + j;
            float v = fast_tanh(acc[mi][j] + bb);
            if (last) outf[(size_t)m * 512 + n] = v;
            else      outb[(size_t)m * 512 + n] = f2bf(v);
        }
    }
}

extern "C" void kernel_launch(void* const* d_in, const int* in_sizes, int n_in,
                              void* d_out, int out_size, void* d_ws, size_t ws_size,
                              hipStream_t stream) {
    const int*   ids  = (const int*)d_in[0];
    const float* emb  = (const float*)d_in[1];
    const float* W    = (const float*)d_in[2];
    const float* bias = (const float*)d_in[3];
    float* out = (float*)d_out;

    // ws (ushorts): Wb 524288 | embT 16384000 | PQ 32768000 | hB 33554432 | hA 16777216
    unsigned short* Wb   = (unsigned short*)d_ws;
    unsigned short* embT = Wb + 524288;
    unsigned short* PQ   = embT + 16384000;
    unsigned short* hB   = PQ + 32768000;
    unsigned short* hA   = hB + 33554432;

    wconv<<<512, 256, 0, stream>>>((const float4*)W, (ushort4*)Wb);
    tconv<<<16000, 256, 0, stream>>>((const float4*)emb, (ushort4*)embT);

    pq_gemm<<<2000, 256, 0, stream>>>(embT, Wb, PQ);          // P,Q tables
    lvl1_add<<<16384, 256, 0, stream>>>(ids, PQ, bias, hB);   // level 1 -> hB

    int M = 32768;
    for (int l = 2; l <= 4; ++l) {                 // in: hB,hA,hB -> out: hA,hB,hA
        const unsigned short* in = (l & 1) ? hA : hB;
        unsigned short*       ob = (l & 1) ? hB : hA;
        level_gemm<<<(M / 128) * 4, 256, 0, stream>>>(in, Wb, bias, ob, M);
        M >>= 1;
    }
    for (int l = 5; l <= 11; ++l) {                // Mout = 4096..64
        const unsigned short* in = (l & 1) ? hA : hB;
        unsigned short*       ob = (l & 1) ? hB : hA;
        small_gemm<<<(M / 64) * 8, 256, 0, stream>>>(in, Wb, bias, ob, out,
                                                     l == 11 ? 1 : 0);
        M >>= 1;
    }
}